// Round 6
// baseline (1388.903 us; speedup 1.0000x reference)
//
#include <hip/hip_runtime.h>
#include <math.h>

typedef __attribute__((ext_vector_type(4))) float floatx4;
typedef __attribute__((ext_vector_type(2))) float floatx2;

#define ROWP 256          // logical row length (fp8 bytes); stored as TWO 128-B planes
#define NT 14             // packed weight col-tiles (layout)
#define NTC 13            // used col-tiles (13 x 16 = 208 cols; 200 real)
#define KS 7              // 7 x 32 = 224 K (200 real + pad)
#define PACK_BYTES (NT*KS*64*8)   // bytes per packed fp8 weight matrix (layers 2..5)
#define PACK1_BYTES (NT*64*8)     // layer-1 packed fp8 weight (K=32)
#define STAGE_BYTES (NTC*KS*64*8) // 46592 B staged per phase in sage
#define BSHIFT 6          // 64 nodes per CSR bucket
#define EPB 4096          // edges per binning block
#define MAXBUCK 1600      // LDS capacity for bucket arrays (>= nbuck=1563)
#define PT_STRIDE 208     // fp8 bytes per pool-tile row (13 uint4)

// h/agg storage: plane-halved for L2 temporal blocking of the gather.
//   plane 0: cols   0..127, N x 128 B contiguous (12.8 MB)
//   plane 1: cols 128..255, N x 128 B contiguous (cols 200.. are zero pad)
// One gather dispatch touches ONE plane (12.8 MB working set vs 4 MB/XCD L2).

__device__ __forceinline__ unsigned short f2bf(float f){
    union { float f; unsigned u; } v; v.f = f;
    unsigned r = v.u + 0x7FFF + ((v.u >> 16) & 1);
    return (unsigned short)(r >> 16);
}
__device__ __forceinline__ unsigned pk4_fp8(float a, float b, float c, float d){
    int w = __builtin_amdgcn_cvt_pk_fp8_f32(a, b, 0, false);
    w = __builtin_amdgcn_cvt_pk_fp8_f32(c, d, w, true);
    return (unsigned)w;
}
__device__ __forceinline__ unsigned char b1_fp8(float a){
    int w = __builtin_amdgcn_cvt_pk_fp8_f32(a, a, 0, false);
    return (unsigned char)(w & 0xFF);
}

// ============================ binned CSR build (no hot global atomics) ============================

__global__ __launch_bounds__(256) void k_bin_hist(
    const int* __restrict__ dst, int* __restrict__ hist, int E, int nbuck)
{
    __shared__ int lh[MAXBUCK];
    for (int i = threadIdx.x; i < nbuck; i += 256) lh[i] = 0;
    __syncthreads();
    int base = blockIdx.x * EPB;
    #pragma unroll
    for (int k = 0; k < EPB / 256; ++k){
        int e = base + k * 256 + threadIdx.x;
        if (e < E) atomicAdd(&lh[dst[e] >> BSHIFT], 1);
    }
    __syncthreads();
    for (int i = threadIdx.x; i < nbuck; i += 256)
        hist[(size_t)blockIdx.x * nbuck + i] = lh[i];
}

__global__ __launch_bounds__(256) void k_col_scan(
    int* __restrict__ hist, int* __restrict__ T, int nblk, int nbuck)
{
    __shared__ int part[4][64];
    int w = threadIdx.x >> 6, l = threadIdx.x & 63;
    int b = blockIdx.x * 64 + l;
    int chunk = (nblk + 3) >> 2;
    int j0 = w * chunk, j1 = j0 + chunk; if (j1 > nblk) j1 = nblk;
    int s = 0;
    if (b < nbuck)
        for (int j = j0; j < j1; ++j) s += hist[(size_t)j * nbuck + b];
    part[w][l] = s;
    __syncthreads();
    if (b < nbuck){
        int run = 0;
        for (int w2 = 0; w2 < w; ++w2) run += part[w2][l];
        for (int j = j0; j < j1; ++j){
            int v = hist[(size_t)j * nbuck + b];
            hist[(size_t)j * nbuck + b] = run;
            run += v;
        }
        if (w == 3) T[b] = part[0][l] + part[1][l] + part[2][l] + part[3][l];
    }
}

__global__ __launch_bounds__(256) void k_scan_t(
    const int* __restrict__ T, int* __restrict__ tbase, int nbuck)
{
    __shared__ int ts[256];
    int t = threadIdx.x;
    int v[8]; int s = 0;
    int base = t * 8;
    #pragma unroll
    for (int k = 0; k < 8; ++k){
        int idx = base + k;
        v[k] = (idx < nbuck) ? T[idx] : 0;
        s += v[k];
    }
    ts[t] = s; __syncthreads();
    #pragma unroll
    for (int off = 1; off < 256; off <<= 1){
        int p = (t >= off) ? ts[t - off] : 0;
        __syncthreads();
        ts[t] += p;
        __syncthreads();
    }
    int run = ts[t] - s;
    #pragma unroll
    for (int k = 0; k < 8; ++k){
        int idx = base + k;
        if (idx < nbuck) tbase[idx] = run;
        run += v[k];
    }
    if (t == 255) tbase[nbuck] = ts[255];
}

// pairs packed into 4 B: (dst&63) << 26 | src   (src < 2^26)
__global__ __launch_bounds__(256) void k_bin_scatter(
    const int* __restrict__ src, const int* __restrict__ dst,
    const int* __restrict__ off, const int* __restrict__ tbase,
    unsigned* __restrict__ pairs, int E, int nbuck)
{
    __shared__ int lbase[MAXBUCK];
    __shared__ int lc[MAXBUCK];
    for (int i = threadIdx.x; i < nbuck; i += 256){
        lbase[i] = off[(size_t)blockIdx.x * nbuck + i] + tbase[i];
        lc[i] = 0;
    }
    __syncthreads();
    int base = blockIdx.x * EPB;
    #pragma unroll
    for (int k = 0; k < EPB / 256; ++k){
        int e = base + k * 256 + threadIdx.x;
        if (e < E){
            int d = dst[e];
            int b = d >> BSHIFT;
            int r = atomicAdd(&lc[b], 1);
            pairs[lbase[b] + r] = ((unsigned)(d & 63) << 26) | (unsigned)src[e];
        }
    }
}

// bucket degree count + inv_deg (fused)
__global__ __launch_bounds__(256) void k_bucket_deg(
    const unsigned* __restrict__ pairs, const int* __restrict__ tbase,
    int* __restrict__ deg, float* __restrict__ inv_deg, int N)
{
    __shared__ int ld[64];
    int b = blockIdx.x;
    if (threadIdx.x < 64) ld[threadIdx.x] = 0;
    __syncthreads();
    int pb = tbase[b], pe = tbase[b + 1];
    for (int e = pb + threadIdx.x; e < pe; e += 256)
        atomicAdd(&ld[pairs[e] >> 26], 1);
    __syncthreads();
    if (threadIdx.x < 64){
        int node = (b << BSHIFT) + threadIdx.x;
        if (node < N){
            int d = ld[threadIdx.x];
            deg[node] = d;
            inv_deg[node] = 1.0f / fmaxf((float)d, 1.0f);
        }
    }
}

__global__ __launch_bounds__(256) void k_place(
    const unsigned* __restrict__ pairs, const int* __restrict__ tbase,
    const int* __restrict__ row_ptr, int* __restrict__ srcs, int N)
{
    __shared__ int lrp[64];
    __shared__ int lcur[64];
    int b = blockIdx.x;
    if (threadIdx.x < 64){
        int node = (b << BSHIFT) + threadIdx.x;
        lrp[threadIdx.x] = (node < N) ? row_ptr[node] : 0;
        lcur[threadIdx.x] = 0;
    }
    __syncthreads();
    int pb = tbase[b], pe = tbase[b + 1];
    for (int e = pb + threadIdx.x; e < pe; e += 256){
        unsigned pr = pairs[e];
        int li = pr >> 26;
        int r = atomicAdd(&lcur[li], 1);
        srcs[lrp[li] + r] = (int)(pr & 0x03FFFFFFu);
    }
}

// ============================ row_ptr scan (over deg) ============================

__global__ void k_scan_sums(const int* __restrict__ deg, int* __restrict__ csum, int N){
    __shared__ int sd[256];
    int base = blockIdx.x * 1024;
    int s = 0;
    for (int i = threadIdx.x; i < 1024; i += 256){
        int idx = base + i;
        s += (idx < N) ? deg[idx] : 0;
    }
    sd[threadIdx.x] = s; __syncthreads();
    for (int off = 128; off > 0; off >>= 1){
        if (threadIdx.x < off) sd[threadIdx.x] += sd[threadIdx.x + off];
        __syncthreads();
    }
    if (threadIdx.x == 0) csum[blockIdx.x] = sd[0];
}

__global__ void k_scan_apply(const int* __restrict__ deg, const int* __restrict__ csum,
                             int* __restrict__ row_ptr, int N, int E, int nchunks){
    __shared__ int ts[256];
    __shared__ int base_s;
    int partial = 0;
    for (int j = threadIdx.x; j < nchunks; j += 256)
        if (j < (int)blockIdx.x) partial += csum[j];
    ts[threadIdx.x] = partial; __syncthreads();
    for (int off = 128; off > 0; off >>= 1){
        if (threadIdx.x < off) ts[threadIdx.x] += ts[threadIdx.x + off];
        __syncthreads();
    }
    if (threadIdx.x == 0) base_s = ts[0];
    __syncthreads();
    int blk_base = base_s;
    __syncthreads();   // everyone read base_s; ts about to be reused

    int base = blockIdx.x * 1024 + threadIdx.x * 4;
    int v[4]; int s = 0;
    #pragma unroll
    for (int j = 0; j < 4; ++j){
        int idx = base + j;
        v[j] = (idx < N) ? deg[idx] : 0;
        s += v[j];
    }
    ts[threadIdx.x] = s; __syncthreads();
    #pragma unroll
    for (int off = 1; off < 256; off <<= 1){
        int t = (threadIdx.x >= off) ? ts[threadIdx.x - off] : 0;
        __syncthreads();
        ts[threadIdx.x] += t;
        __syncthreads();
    }
    int excl = ts[threadIdx.x] - s + blk_base;
    #pragma unroll
    for (int j = 0; j < 4; ++j){
        int idx = base + j;
        if (idx < N) row_ptr[idx] = excl;
        excl += v[j];
    }
    if (blockIdx.x == 0 && threadIdx.x == 0) row_ptr[N] = E;
}

// ============================ graph segment starts (binary search) ============================

__global__ void k_gstart_bs(const int* __restrict__ batch, int* __restrict__ gstart,
                            int N, int NG){
    int g = blockIdx.x * blockDim.x + threadIdx.x;
    if (g > NG) return;
    int lo = 0, hi = N;
    while (lo < hi){
        int mid = (lo + hi) >> 1;
        if (batch[mid] < g) lo = mid + 1; else hi = mid;
    }
    gstart[g] = lo;
}

// ============================ packing (fp8) ============================

__global__ void k_pack_w(const float* W0, const float* W1, const float* W2, const float* W3,
                         const float* W4, const float* W5, const float* W6, const float* W7,
                         unsigned char* __restrict__ out){
    const float* Ws[8] = {W0,W1,W2,W3,W4,W5,W6,W7};
    const float* W = Ws[blockIdx.z];
    int lane = threadIdx.x;
    int n  = blockIdx.x * 16 + (lane & 15);
    int k0 = blockIdx.y * 32 + (lane >> 4) * 8;
    float f[8];
    #pragma unroll
    for (int j = 0; j < 8; ++j){
        int k = k0 + j;
        f[j] = (n < 200 && k < 200) ? W[n * 200 + k] : 0.f;
    }
    uint2 u;
    u.x = pk4_fp8(f[0], f[1], f[2], f[3]);
    u.y = pk4_fp8(f[4], f[5], f[6], f[7]);
    size_t off = ((((size_t)blockIdx.z * NT + blockIdx.x) * KS + blockIdx.y) * 64 + lane) * 8;
    *reinterpret_cast<uint2*>(out + off) = u;
}

// combined: pack_x (blocks 0..xblk-1), pack_w1 (next NT blocks), pack_b (next 5)
__global__ __launch_bounds__(256) void k_pack_misc(
    const float* __restrict__ x, unsigned short* __restrict__ xp,
    unsigned char* __restrict__ xa,
    const float* __restrict__ Wl1, const float* __restrict__ Wr1,
    unsigned char* __restrict__ w1pack,
    const float* b0, const float* b1, const float* b2, const float* b3, const float* b4,
    float* __restrict__ biasp, int N, int xblk)
{
    int bid = blockIdx.x;
    if (bid < xblk){
        int i = bid * 256 + threadIdx.x;
        int node = i >> 4, c = i & 15;
        if (node < N){
            float f = (c < 11) ? x[(size_t)node * 11 + c] : 0.f;
            xp[i] = f2bf(f);
            xa[(size_t)node * 32 + 16 + c] = b1_fp8(f);
        }
        return;
    }
    int j = bid - xblk;
    if (j < NT){
        if (threadIdx.x >= 64) return;
        int lane = threadIdx.x;
        int n  = j * 16 + (lane & 15);
        int k0 = (lane >> 4) * 8;
        float f[8];
        #pragma unroll
        for (int jj = 0; jj < 8; ++jj){
            int k = k0 + jj;
            float v = 0.f;
            if (n < 200){
                if (k < 11)                 v = Wl1[n * 11 + k];
                else if (k >= 16 && k < 27) v = Wr1[n * 11 + (k - 16)];
            }
            f[jj] = v;
        }
        uint2 u;
        u.x = pk4_fp8(f[0], f[1], f[2], f[3]);
        u.y = pk4_fp8(f[4], f[5], f[6], f[7]);
        size_t off = ((size_t)j * 64 + lane) * 8;
        *reinterpret_cast<uint2*>(w1pack + off) = u;
        return;
    }
    int l = j - NT;   // 0..4
    const float* bs[5] = {b0,b1,b2,b3,b4};
    int c = threadIdx.x;
    if (c < ROWP) biasp[l * ROWP + c] = (c < 200) ? bs[l][c] : 0.f;
}

// ============================ aggregation (layer 1, K=11) ============================

__global__ __launch_bounds__(256) void k_agg11(
    const unsigned short* __restrict__ xp, const int* __restrict__ row_ptr,
    const int* __restrict__ srcs, const float* __restrict__ inv_deg,
    unsigned char* __restrict__ xa, int N)
{
    int half = threadIdx.x >> 5;              // 0..7
    int node = blockIdx.x * 8 + half;
    int l = threadIdx.x & 31;
    if (node >= N) return;
    int beg = row_ptr[node], end = row_ptr[node + 1];

    float acc[12];
    #pragma unroll
    for (int i = 0; i < 12; ++i) acc[i] = 0.f;

    const uint4* x4 = reinterpret_cast<const uint4*>(xp);
    const uint2* x2 = reinterpret_cast<const uint2*>(xp);
    for (int e = beg + l; e < end; e += 32){
        int sn = srcs[e];
        uint4 a = x4[(size_t)sn * 2];
        uint2 b = x2[(size_t)sn * 4 + 2];
        union { unsigned u; float f; } c;
        c.u = a.x << 16;         acc[0] += c.f;
        c.u = a.x & 0xffff0000u; acc[1] += c.f;
        c.u = a.y << 16;         acc[2] += c.f;
        c.u = a.y & 0xffff0000u; acc[3] += c.f;
        c.u = a.z << 16;         acc[4] += c.f;
        c.u = a.z & 0xffff0000u; acc[5] += c.f;
        c.u = a.w << 16;         acc[6] += c.f;
        c.u = a.w & 0xffff0000u; acc[7] += c.f;
        c.u = b.x << 16;         acc[8] += c.f;
        c.u = b.x & 0xffff0000u; acc[9] += c.f;
        c.u = b.y << 16;         acc[10] += c.f;
        c.u = b.y & 0xffff0000u; acc[11] += c.f;
    }

    #pragma unroll
    for (int i = 0; i < 11; ++i){
        acc[i] += __shfl_xor(acc[i], 1, 64);
        acc[i] += __shfl_xor(acc[i], 2, 64);
        acc[i] += __shfl_xor(acc[i], 4, 64);
        acc[i] += __shfl_xor(acc[i], 8, 64);
        acc[i] += __shfl_xor(acc[i], 16, 64);
    }

    if (l == 0){
        float id = inv_deg[node];
        float v[12];
        #pragma unroll
        for (int i = 0; i < 11; ++i) v[i] = acc[i] * id;
        v[11] = 0.f;
        uint4 o;
        o.x = pk4_fp8(v[0], v[1], v[2], v[3]);
        o.y = pk4_fp8(v[4], v[5], v[6], v[7]);
        o.z = pk4_fp8(v[8], v[9], v[10], v[11]);
        o.w = 0u;
        *reinterpret_cast<uint4*>(xa + (size_t)node * 32) = o;
    }
}

// ============================ gather (layers 2..5) — half-plane version ============================
// One dispatch touches ONE 128-B plane (12.8 MB working set). Wave per node,
// 8 groups x 8 lanes; batched src-index loads + 4-deep row pipeline (proven loop).

__device__ __forceinline__ void accum_fp8v(floatx2* a, uint4 u){
    a[0] += __builtin_amdgcn_cvt_pk_f32_fp8((int)u.x, false);
    a[1] += __builtin_amdgcn_cvt_pk_f32_fp8((int)u.x, true );
    a[2] += __builtin_amdgcn_cvt_pk_f32_fp8((int)u.y, false);
    a[3] += __builtin_amdgcn_cvt_pk_f32_fp8((int)u.y, true );
    a[4] += __builtin_amdgcn_cvt_pk_f32_fp8((int)u.z, false);
    a[5] += __builtin_amdgcn_cvt_pk_f32_fp8((int)u.z, true );
    a[6] += __builtin_amdgcn_cvt_pk_f32_fp8((int)u.w, false);
    a[7] += __builtin_amdgcn_cvt_pk_f32_fp8((int)u.w, true );
}

__global__ __launch_bounds__(256) void k_agg200h(
    const unsigned char* __restrict__ hpl, const int* __restrict__ row_ptr,
    const int* __restrict__ srcs, const float* __restrict__ inv_deg,
    unsigned char* __restrict__ aggpl, int N)
{
    int node = blockIdx.x * 4 + (threadIdx.x >> 6);
    int lane = threadIdx.x & 63;
    if (node >= N) return;
    int g = lane >> 3;    // group 0..7
    int l = lane & 7;     // lane-in-group: 8 x 16 B = one 128-B plane row
    int beg = row_ptr[node], end = row_ptr[node + 1];
    int nb = end - beg;

    floatx2 acc[8];
    #pragma unroll
    for (int i = 0; i < 8; ++i) acc[i] = (floatx2){0.f, 0.f};

    const uint4* h4 = reinterpret_cast<const uint4*>(hpl);

    for (int t = 0; t < nb; t += 64){
        int cnt = nb - t; if (cnt > 64) cnt = 64;
        // one coalesced load of up to 64 src indices for this node
        int eidx = t + lane;
        int si = srcs[beg + (eidx < nb ? eidx : nb - 1)];
        // group g handles batch-local edges j = g, g+8, g+16, ...  (j < cnt)
        int jmax = (cnt - g + 7) >> 3;     // >= 0 since cnt >= 1, g <= 7

        int j = 0;
        for (; j + 4 <= jmax; j += 4){
            int b0 = g + 8 * j;
            int s0 = __shfl(si, b0,      64);
            int s1 = __shfl(si, b0 + 8,  64);
            int s2 = __shfl(si, b0 + 16, 64);
            int s3 = __shfl(si, b0 + 24, 64);
            uint4 u0 = h4[(size_t)s0 * 8 + l];
            uint4 u1 = h4[(size_t)s1 * 8 + l];
            uint4 u2 = h4[(size_t)s2 * 8 + l];
            uint4 u3 = h4[(size_t)s3 * 8 + l];
            accum_fp8v(acc, u0);
            accum_fp8v(acc, u1);
            accum_fp8v(acc, u2);
            accum_fp8v(acc, u3);
        }
        for (; j < jmax; ++j){
            int s0 = __shfl(si, g + 8 * j, 64);
            uint4 u0 = h4[(size_t)s0 * 8 + l];
            accum_fp8v(acc, u0);
        }
    }

    float af[16];
    #pragma unroll
    for (int i = 0; i < 8; ++i){ af[2*i] = acc[i][0]; af[2*i+1] = acc[i][1]; }
    #pragma unroll
    for (int i = 0; i < 16; ++i){
        af[i] += __shfl_xor(af[i], 8, 64);
        af[i] += __shfl_xor(af[i], 16, 64);
        af[i] += __shfl_xor(af[i], 32, 64);
    }

    if (g == 0){   // lanes 0..7 hold the group-summed row
        float id = inv_deg[node];
        uint4 o;
        o.x = pk4_fp8(af[0] * id,  af[1] * id,  af[2] * id,  af[3] * id);
        o.y = pk4_fp8(af[4] * id,  af[5] * id,  af[6] * id,  af[7] * id);
        o.z = pk4_fp8(af[8] * id,  af[9] * id,  af[10] * id, af[11] * id);
        o.w = pk4_fp8(af[12] * id, af[13] * id, af[14] * id, af[15] * id);
        *reinterpret_cast<uint4*>(aggpl + (size_t)node * 128 + l * 16) = o;
    }
}

// ============================ layer-1 MFMA + fused pool ============================

__global__ __launch_bounds__(256) void k_layer1_mfma(
    const unsigned char* __restrict__ xa, const unsigned char* __restrict__ W1p,
    const float* __restrict__ biasp, const int* __restrict__ batch,
    float* __restrict__ gsum, unsigned char* __restrict__ outp, int M)
{
    __shared__ __align__(16) unsigned char ptile[64 * PT_STRIDE];
    __shared__ int lb[64];
    const int wave = threadIdx.x >> 6;
    const int lane = threadIdx.x & 63;
    const int n = lane & 15;
    const int q = lane >> 4;
    const int r0 = blockIdx.x * 64;
    const int nrows = (M - r0 < 64) ? (M - r0) : 64;
    int row = r0 + wave * 16 + n;
    int rowc = row < M ? row : (M - 1);

    if (threadIdx.x < 64 && threadIdx.x < nrows) lb[threadIdx.x] = batch[r0 + threadIdx.x];

    long a = *reinterpret_cast<const long*>(xa + (size_t)rowc * 32 + q * 8);

    floatx4 acc[NTC];
    #pragma unroll
    for (int nt = 0; nt < NTC; ++nt){
        long b = *reinterpret_cast<const long*>(W1p + ((size_t)nt * 64 + lane) * 8);
        acc[nt] = __builtin_amdgcn_mfma_f32_16x16x32_fp8_fp8(a, b, (floatx4){0.f,0.f,0.f,0.f}, 0, 0, 0);
    }

    // epilogue -> LDS pool tile
    {
        int lr0 = wave * 16 + q * 4;
        #pragma unroll
        for (int nt = 0; nt < NTC; ++nt){
            float bsv = biasp[nt * 16 + n];
            #pragma unroll
            for (int r = 0; r < 4; ++r){
                float v = fmaxf(acc[nt][r] + bsv, 0.f);
                ptile[(lr0 + r) * PT_STRIDE + nt * 16 + n] = b1_fp8(v);
            }
        }
    }
    __syncthreads();

    // vectorized tile -> global h write (plane-halved layout)
    {
        unsigned char* out0 = outp;
        unsigned char* out1 = outp + (size_t)M * 128;
        const uint4* s4 = reinterpret_cast<const uint4*>(ptile);
        int tot = nrows * 13;
        for (int i = threadIdx.x; i < tot; i += 256){
            int r = i / 13, c = i - r * 13;
            unsigned char* dst = (c < 8)
                ? out0 + (size_t)(r0 + r) * 128 + c * 16
                : out1 + (size_t)(r0 + r) * 128 + (c - 8) * 16;
            *reinterpret_cast<uint4*>(dst) = s4[i];
        }
    }

    // segmented pool reduce (batch sorted -> few segments per block)
    if (threadIdx.x < 50){
        int t = threadIdx.x;
        const unsigned* pd = reinterpret_cast<const unsigned*>(ptile);
        float s0 = 0.f, s1 = 0.f, s2 = 0.f, s3 = 0.f;
        int cur = lb[0];
        for (int r = 0; r < nrows; ++r){
            int gg = lb[r];
            if (gg != cur){
                float* gp = &gsum[(size_t)cur * 1000 + t * 4];
                atomicAdd(gp + 0, s0); atomicAdd(gp + 1, s1);
                atomicAdd(gp + 2, s2); atomicAdd(gp + 3, s3);
                s0 = s1 = s2 = s3 = 0.f;
                cur = gg;
            }
            unsigned u = pd[r * 52 + t];
            floatx2 lo = __builtin_amdgcn_cvt_pk_f32_fp8((int)u, false);
            floatx2 hi = __builtin_amdgcn_cvt_pk_f32_fp8((int)u, true);
            s0 += lo[0]; s1 += lo[1]; s2 += hi[0]; s3 += hi[1];
        }
        float* gp = &gsum[(size_t)cur * 1000 + t * 4];
        atomicAdd(gp + 0, s0); atomicAdd(gp + 1, s1);
        atomicAdd(gp + 2, s2); atomicAdd(gp + 3, s3);
    }
}

// ============================ MFMA SAGE GEMM + fused pool (layers 2..5) ============================
// A rows read from plane-halved layout; lw reused as pool tile after MFMA.
__global__ __launch_bounds__(256) void k_sage_mfma(
    const unsigned char* __restrict__ Aagg, const unsigned char* __restrict__ Ah,
    const unsigned char* __restrict__ Wlp, const unsigned char* __restrict__ Wrp,
    const float* __restrict__ biasp, const int* __restrict__ batch,
    float* __restrict__ gsum, int col_off,
    unsigned char* __restrict__ outp, int M)
{
    __shared__ __align__(16) unsigned char lw[STAGE_BYTES];   // 45.5 KB (weights, then pool tile)
    __shared__ int lb[64];
    const int wave = threadIdx.x >> 6;
    const int lane = threadIdx.x & 63;
    const int n = lane & 15;
    const int q = lane >> 4;
    const int r0 = blockIdx.x * 64;
    const int nrows = (M - r0 < 64) ? (M - r0) : 64;
    int row = r0 + wave * 16 + n;
    int rowc = row < M ? row : (M - 1);

    if (threadIdx.x < 64 && threadIdx.x < nrows) lb[threadIdx.x] = batch[r0 + threadIdx.x];

    floatx4 acc[NTC];
    #pragma unroll
    for (int nt = 0; nt < NTC; ++nt) acc[nt] = (floatx4){0.f, 0.f, 0.f, 0.f};

    const unsigned char* Wp[2] = {Wlp, Wrp};
    const unsigned char* Ap[2] = {Aagg, Ah};
    const size_t plane = (size_t)M * 128;

    #pragma unroll
    for (int phase = 0; phase < 2; ++phase){
        if (phase) __syncthreads();   // all waves done reading previous phase
        {
            const uint4* src4 = reinterpret_cast<const uint4*>(Wp[phase]);
            uint4* dst4 = reinterpret_cast<uint4*>(lw);
            for (int i = threadIdx.x; i < STAGE_BYTES / 16; i += 256)
                dst4[i] = src4[i];
        }
        __syncthreads();

        const unsigned char* A0 = Ap[phase] + (size_t)rowc * 128 + q * 8;
        const unsigned char* A1 = A0 + plane;
        long a[KS];
        #pragma unroll
        for (int ks = 0; ks < 4; ++ks)
            a[ks] = *reinterpret_cast<const long*>(A0 + ks * 32);
        #pragma unroll
        for (int ks = 4; ks < KS; ++ks)
            a[ks] = *reinterpret_cast<const long*>(A1 + (ks - 4) * 32);

        #pragma unroll
        for (int ks = 0; ks < KS; ++ks){
            #pragma unroll
            for (int nt = 0; nt < NTC; ++nt){
                long b = *reinterpret_cast<const long*>(&lw[((nt * KS + ks) * 64 + lane) * 8]);
                acc[nt] = __builtin_amdgcn_mfma_f32_16x16x32_fp8_fp8(a[ks], b, acc[nt], 0, 0, 0);
            }
        }
    }
    __syncthreads();   // all MFMA done reading lw; reuse as pool tile

    unsigned char* ptile = lw;
    {
        int lr0 = wave * 16 + q * 4;
        #pragma unroll
        for (int nt = 0; nt < NTC; ++nt){
            float bsv = biasp[nt * 16 + n];
            #pragma unroll
            for (int r = 0; r < 4; ++r){
                float v = fmaxf(acc[nt][r] + bsv, 0.f);
                ptile[(lr0 + r) * PT_STRIDE + nt * 16 + n] = b1_fp8(v);
            }
        }
    }
    __syncthreads();   // pool tile complete

    // vectorized tile -> global h write (plane-halved layout; pads stay zero from memset)
    {
        unsigned char* out0 = outp;
        unsigned char* out1 = outp + plane;
        const uint4* s4 = reinterpret_cast<const uint4*>(ptile);
        int tot = nrows * 13;
        for (int i = threadIdx.x; i < tot; i += 256){
            int r = i / 13, c = i - r * 13;
            unsigned char* dst = (c < 8)
                ? out0 + (size_t)(r0 + r) * 128 + c * 16
                : out1 + (size_t)(r0 + r) * 128 + (c - 8) * 16;
            *reinterpret_cast<uint4*>(dst) = s4[i];
        }
    }

    // segmented pool reduce (batch sorted -> few segments per block)
    if (threadIdx.x < 50){
        int t = threadIdx.x;
        const unsigned* pd = reinterpret_cast<const unsigned*>(ptile);
        float s0 = 0.f, s1 = 0.f, s2 = 0.f, s3 = 0.f;
        int cur = lb[0];
        for (int r = 0; r < nrows; ++r){
            int gg = lb[r];
            if (gg != cur){
                float* gp = &gsum[(size_t)cur * 1000 + col_off + t * 4];
                atomicAdd(gp + 0, s0); atomicAdd(gp + 1, s1);
                atomicAdd(gp + 2, s2); atomicAdd(gp + 3, s3);
                s0 = s1 = s2 = s3 = 0.f;
                cur = gg;
            }
            unsigned u = pd[r * 52 + t];
            floatx2 lo = __builtin_amdgcn_cvt_pk_f32_fp8((int)u, false);
            floatx2 hi = __builtin_amdgcn_cvt_pk_f32_fp8((int)u, true);
            s0 += lo[0]; s1 += lo[1]; s2 += hi[0]; s3 += hi[1];
        }
        float* gp = &gsum[(size_t)cur * 1000 + col_off + t * 4];
        atomicAdd(gp + 0, s0); atomicAdd(gp + 1, s1);
        atomicAdd(gp + 2, s2); atomicAdd(gp + 3, s3);
    }
}

// ============================ MLP head (fp32) ============================

__global__ __launch_bounds__(256) void k_mlp_first(
    const float* __restrict__ gsum, const int* __restrict__ gstart,
    const float* __restrict__ W, const float* __restrict__ b,
    float* __restrict__ outp)
{
    __shared__ __align__(16) float row[1000];
    int g = blockIdx.x;
    int cnt = gstart[g+1] - gstart[g];
    float inv = 1.0f / fmaxf((float)cnt, 1.0f);
    for (int i = threadIdx.x; i < 1000; i += 256)
        row[i] = gsum[(size_t)g * 1000 + i] * inv;
    __syncthreads();
    for (int c = threadIdx.x; c < 500; c += 256){
        const float4* w4 = reinterpret_cast<const float4*>(W + (size_t)c * 1000);
        const float4* r4 = reinterpret_cast<const float4*>(row);
        float s = b[c];
        for (int k = 0; k < 250; ++k){
            float4 wv = w4[k]; float4 rv = r4[k];
            s = fmaf(wv.x, rv.x, s);
            s = fmaf(wv.y, rv.y, s);
            s = fmaf(wv.z, rv.z, s);
            s = fmaf(wv.w, rv.w, s);
        }
        outp[(size_t)g * 500 + c] = s;
    }
}

__global__ __launch_bounds__(256) void k_mlp23(
    const float* __restrict__ t1, const float* __restrict__ W2,
    const float* __restrict__ b2, const float* __restrict__ W3,
    const float* __restrict__ b3, float* __restrict__ outp)
{
    __shared__ __align__(16) float row[500];
    __shared__ float red[256];
    int g = blockIdx.x;
    for (int i = threadIdx.x; i < 500; i += 256) row[i] = t1[(size_t)g * 500 + i];
    __syncthreads();
    float prod = 0.f;
    int c = threadIdx.x;
    if (c < 250){
        const float4* w4 = reinterpret_cast<const float4*>(W2 + (size_t)c * 500);
        const float4* r4 = reinterpret_cast<const float4*>(row);
        float s = b2[c];
        for (int k = 0; k < 125; ++k){
            float4 wv = w4[k]; float4 rv = r4[k];
            s = fmaf(wv.x, rv.x, s);
            s = fmaf(wv.y, rv.y, s);
            s = fmaf(wv.z, rv.z, s);
            s = fmaf(wv.w, rv.w, s);
        }
        prod = s * W3[c];
    }
    red[threadIdx.x] = prod;
    __syncthreads();
    for (int off = 128; off > 0; off >>= 1){
        if (threadIdx.x < off) red[threadIdx.x] += red[threadIdx.x + off];
        __syncthreads();
    }
    if (threadIdx.x == 0)
        outp[g] = 1.0f / (1.0f + expf(-(red[0] + b3[0])));
}

// ============================ launch ============================

extern "C" void kernel_launch(void* const* d_in, const int* in_sizes, int n_in,
                              void* d_out, int out_size, void* d_ws, size_t ws_size,
                              hipStream_t stream)
{
    const float* x    = (const float*)d_in[0];
    const int*   ei   = (const int*)d_in[1];
    const int*   batch= (const int*)d_in[2];
    const float* Wl[5]; const float* bl[5]; const float* Wr[5];
    for (int i = 0; i < 5; ++i){
        Wl[i] = (const float*)d_in[3 + 3*i];
        bl[i] = (const float*)d_in[4 + 3*i];
        Wr[i] = (const float*)d_in[5 + 3*i];
    }
    const float* pw1 = (const float*)d_in[18]; const float* pb1 = (const float*)d_in[19];
    const float* pw2 = (const float*)d_in[20]; const float* pb2 = (const float*)d_in[21];
    const float* pw3 = (const float*)d_in[22]; const float* pb3 = (const float*)d_in[23];
    float* out = (float*)d_out;

    const int N  = in_sizes[2];
    const int E  = in_sizes[1] / 2;
    const int NG = out_size;
    const int* esrc = ei;
    const int* edst = ei + E;
    const int nbuck = (N + 63) >> BSHIFT;          // 1563
    const int nblk  = (E + EPB - 1) / EPB;         // 782

    // ---- workspace carve ----
    char* p = (char*)d_ws;
    auto carve = [&](size_t bytes)->void* {
        void* r = (void*)p;
        p += (bytes + 255) & ~(size_t)255;
        return r;
    };
    int*   deg     = (int*)  carve((size_t)N * 4);
    int*   row_ptr = (int*)  carve(((size_t)N + 1) * 4);
    int*   csum    = (int*)  carve(4096);
    int*   hist    = (int*)  carve((size_t)nblk * nbuck * 4);
    int*   Tb      = (int*)  carve((size_t)nbuck * 4);
    int*   tbase   = (int*)  carve(((size_t)nbuck + 1) * 4);
    float* invdeg  = (float*)carve((size_t)N * 4);
    int*   gstart  = (int*)  carve(((size_t)NG + 1) * 4);
    int*   srcs    = (int*)  carve((size_t)E * 4);
    unsigned* pairs = (unsigned*)carve((size_t)E * 4);
    unsigned short* xp    = (unsigned short*)carve((size_t)N * 16 * 2);
    unsigned char*  xa    = (unsigned char*) carve((size_t)N * 32);
    unsigned char*  agg8  = (unsigned char*) carve((size_t)N * ROWP);   // 2 planes
    unsigned char*  h8A   = (unsigned char*) carve((size_t)N * ROWP);   // 2 planes
    unsigned char*  h8B   = (unsigned char*) carve((size_t)N * ROWP);   // 2 planes
    unsigned char*  wpack = (unsigned char*) carve((size_t)8 * PACK_BYTES);
    unsigned char*  w1pack= (unsigned char*) carve((size_t)PACK1_BYTES);
    float* biasp   = (float*)carve((size_t)5 * ROWP * 4);
    float* gsum    = (float*)carve((size_t)NG * 1000 * 4);
    float* t1      = (float*)carve((size_t)NG * 500 * 4);

    // ---- zero what must be zero ----
    hipMemsetAsync(gsum, 0, (size_t)NG * 1000 * 4, stream);
    // h plane-1 pad columns (200..255) must stay zero across all layers
    hipMemsetAsync(h8A, 0, (size_t)N * ROWP, stream);
    hipMemsetAsync(h8B, 0, (size_t)N * ROWP, stream);

    // ---- packing ----
    int xblk = (N * 16 + 255) / 256;
    k_pack_w<<<dim3(NT, KS, 8), 64, 0, stream>>>(
        Wl[1], Wr[1], Wl[2], Wr[2], Wl[3], Wr[3], Wl[4], Wr[4], wpack);
    k_pack_misc<<<xblk + NT + 5, 256, 0, stream>>>(
        x, xp, xa, Wl[0], Wr[0], w1pack,
        bl[0], bl[1], bl[2], bl[3], bl[4], biasp, N, xblk);

    // ---- binned CSR build (no hot global atomics) ----
    k_bin_hist<<<nblk, 256, 0, stream>>>(edst, hist, E, nbuck);
    k_col_scan<<<(nbuck + 63) / 64, 256, 0, stream>>>(hist, Tb, nblk, nbuck);
    k_scan_t<<<1, 256, 0, stream>>>(Tb, tbase, nbuck);
    k_bin_scatter<<<nblk, 256, 0, stream>>>(esrc, edst, hist, tbase, pairs, E, nbuck);
    k_bucket_deg<<<nbuck, 256, 0, stream>>>(pairs, tbase, deg, invdeg, N);
    int nchunks = (N + 1023) / 1024;
    k_scan_sums<<<nchunks, 256, 0, stream>>>(deg, csum, N);
    k_scan_apply<<<nchunks, 256, 0, stream>>>(deg, csum, row_ptr, N, E, nchunks);
    k_place<<<nbuck, 256, 0, stream>>>(pairs, tbase, row_ptr, srcs, N);

    // ---- graph starts (binary search over sorted batch) ----
    k_gstart_bs<<<(NG + 256) / 256, 256, 0, stream>>>(batch, gstart, N, NG);

    // ---- layer 1 (fp8 MFMA over K=32 = [agg11 | x11]) + fused pool ----
    int gb = (N + 63) / 64;
    k_agg11<<<(N + 7) / 8, 256, 0, stream>>>(xp, row_ptr, srcs, invdeg, xa, N);
    k_layer1_mfma<<<gb, 256, 0, stream>>>(xa, w1pack, biasp, batch, gsum, h8A, N);

    // ---- layers 2..5 (half-plane fp8 gather x2 + fp8 MFMA + fused pool) ----
    unsigned char* hc = h8A; unsigned char* hn = h8B;
    int ab = (N + 3) / 4;
    size_t plane = (size_t)N * 128;
    for (int L = 1; L < 5; ++L){
        k_agg200h<<<ab, 256, 0, stream>>>(hc,         row_ptr, srcs, invdeg, agg8,         N);
        k_agg200h<<<ab, 256, 0, stream>>>(hc + plane, row_ptr, srcs, invdeg, agg8 + plane, N);
        const unsigned char* Wlp = wpack + (size_t)((L-1)*2 + 0) * PACK_BYTES;
        const unsigned char* Wrp = wpack + (size_t)((L-1)*2 + 1) * PACK_BYTES;
        k_sage_mfma<<<gb, 256, 0, stream>>>(agg8, hc, Wlp, Wrp,
                                            biasp + L * ROWP, batch, gsum, 200 * L,
                                            hn, N);
        unsigned char* t = hc; hc = hn; hn = t;
    }

    // ---- MLP head (pool finalize fused into first layer) ----
    k_mlp_first<<<NG, 256, 0, stream>>>(gsum, gstart, pw1, pb1, t1);
    k_mlp23<<<NG, 256, 0, stream>>>(t1, pw2, pb2, pw3, pb3, out);
}

// Round 7
// 1364.050 us; speedup vs baseline: 1.0182x; 1.0182x over previous
//
#include <hip/hip_runtime.h>
#include <math.h>

typedef __attribute__((ext_vector_type(4))) float floatx4;
typedef __attribute__((ext_vector_type(2))) float floatx2;

#define ROWP 256          // logical row length (fp8 bytes); stored as EIGHT 32-B planes
#define NT 14             // packed weight col-tiles (layout)
#define NTC 13            // used col-tiles (13 x 16 = 208 cols; 200 real)
#define KS 7              // 7 x 32 = 224 K (200 real + pad) = planes 0..6
#define PACK_BYTES (NT*KS*64*8)   // bytes per packed fp8 weight matrix (layers 2..5)
#define PACK1_BYTES (NT*64*8)     // layer-1 packed fp8 weight (K=32)
#define STAGE_BYTES (NTC*KS*64*8) // 46592 B staged per phase in sage
#define BSHIFT 6          // 64 nodes per CSR bucket
#define EPB 4096          // edges per binning block
#define MAXBUCK 1600      // LDS capacity for bucket arrays (>= nbuck=1563)
#define PT_STRIDE 208     // fp8 bytes per pool-tile row (13 uint4)

// h/agg storage: 8 column planes of 32 B/node (plane i = bytes 32i..32i+31,
// N x 32 B contiguous = 3.2 MB). Gather kernel assigns slice = blockIdx & 7;
// hardware round-robin dispatch pins slice s to XCD s, whose 4 MB L2 then
// holds the whole slice -> random row-gathers become L2 hits.
// Planes 0..6 carry K=224 GEMM data (cols 200.. zero pad); plane 7 pure pad.

__device__ __forceinline__ unsigned short f2bf(float f){
    union { float f; unsigned u; } v; v.f = f;
    unsigned r = v.u + 0x7FFF + ((v.u >> 16) & 1);
    return (unsigned short)(r >> 16);
}
__device__ __forceinline__ unsigned pk4_fp8(float a, float b, float c, float d){
    int w = __builtin_amdgcn_cvt_pk_fp8_f32(a, b, 0, false);
    w = __builtin_amdgcn_cvt_pk_fp8_f32(c, d, w, true);
    return (unsigned)w;
}
__device__ __forceinline__ unsigned char b1_fp8(float a){
    int w = __builtin_amdgcn_cvt_pk_fp8_f32(a, a, 0, false);
    return (unsigned char)(w & 0xFF);
}

// ============================ binned CSR build (no hot global atomics) ============================

__global__ __launch_bounds__(256) void k_bin_hist(
    const int* __restrict__ dst, int* __restrict__ hist, int E, int nbuck)
{
    __shared__ int lh[MAXBUCK];
    for (int i = threadIdx.x; i < nbuck; i += 256) lh[i] = 0;
    __syncthreads();
    int base = blockIdx.x * EPB;
    #pragma unroll
    for (int k = 0; k < EPB / 256; ++k){
        int e = base + k * 256 + threadIdx.x;
        if (e < E) atomicAdd(&lh[dst[e] >> BSHIFT], 1);
    }
    __syncthreads();
    for (int i = threadIdx.x; i < nbuck; i += 256)
        hist[(size_t)blockIdx.x * nbuck + i] = lh[i];
}

__global__ __launch_bounds__(256) void k_col_scan(
    int* __restrict__ hist, int* __restrict__ T, int nblk, int nbuck)
{
    __shared__ int part[4][64];
    int w = threadIdx.x >> 6, l = threadIdx.x & 63;
    int b = blockIdx.x * 64 + l;
    int chunk = (nblk + 3) >> 2;
    int j0 = w * chunk, j1 = j0 + chunk; if (j1 > nblk) j1 = nblk;
    int s = 0;
    if (b < nbuck)
        for (int j = j0; j < j1; ++j) s += hist[(size_t)j * nbuck + b];
    part[w][l] = s;
    __syncthreads();
    if (b < nbuck){
        int run = 0;
        for (int w2 = 0; w2 < w; ++w2) run += part[w2][l];
        for (int j = j0; j < j1; ++j){
            int v = hist[(size_t)j * nbuck + b];
            hist[(size_t)j * nbuck + b] = run;
            run += v;
        }
        if (w == 3) T[b] = part[0][l] + part[1][l] + part[2][l] + part[3][l];
    }
}

__global__ __launch_bounds__(256) void k_scan_t(
    const int* __restrict__ T, int* __restrict__ tbase, int nbuck)
{
    __shared__ int ts[256];
    int t = threadIdx.x;
    int v[8]; int s = 0;
    int base = t * 8;
    #pragma unroll
    for (int k = 0; k < 8; ++k){
        int idx = base + k;
        v[k] = (idx < nbuck) ? T[idx] : 0;
        s += v[k];
    }
    ts[t] = s; __syncthreads();
    #pragma unroll
    for (int off = 1; off < 256; off <<= 1){
        int p = (t >= off) ? ts[t - off] : 0;
        __syncthreads();
        ts[t] += p;
        __syncthreads();
    }
    int run = ts[t] - s;
    #pragma unroll
    for (int k = 0; k < 8; ++k){
        int idx = base + k;
        if (idx < nbuck) tbase[idx] = run;
        run += v[k];
    }
    if (t == 255) tbase[nbuck] = ts[255];
}

// pairs packed into 4 B: (dst&63) << 26 | src   (src < 2^26)
__global__ __launch_bounds__(256) void k_bin_scatter(
    const int* __restrict__ src, const int* __restrict__ dst,
    const int* __restrict__ off, const int* __restrict__ tbase,
    unsigned* __restrict__ pairs, int E, int nbuck)
{
    __shared__ int lbase[MAXBUCK];
    __shared__ int lc[MAXBUCK];
    for (int i = threadIdx.x; i < nbuck; i += 256){
        lbase[i] = off[(size_t)blockIdx.x * nbuck + i] + tbase[i];
        lc[i] = 0;
    }
    __syncthreads();
    int base = blockIdx.x * EPB;
    #pragma unroll
    for (int k = 0; k < EPB / 256; ++k){
        int e = base + k * 256 + threadIdx.x;
        if (e < E){
            int d = dst[e];
            int b = d >> BSHIFT;
            int r = atomicAdd(&lc[b], 1);
            pairs[lbase[b] + r] = ((unsigned)(d & 63) << 26) | (unsigned)src[e];
        }
    }
}

// bucket degree count + inv_deg (fused)
__global__ __launch_bounds__(256) void k_bucket_deg(
    const unsigned* __restrict__ pairs, const int* __restrict__ tbase,
    int* __restrict__ deg, float* __restrict__ inv_deg, int N)
{
    __shared__ int ld[64];
    int b = blockIdx.x;
    if (threadIdx.x < 64) ld[threadIdx.x] = 0;
    __syncthreads();
    int pb = tbase[b], pe = tbase[b + 1];
    for (int e = pb + threadIdx.x; e < pe; e += 256)
        atomicAdd(&ld[pairs[e] >> 26], 1);
    __syncthreads();
    if (threadIdx.x < 64){
        int node = (b << BSHIFT) + threadIdx.x;
        if (node < N){
            int d = ld[threadIdx.x];
            deg[node] = d;
            inv_deg[node] = 1.0f / fmaxf((float)d, 1.0f);
        }
    }
}

__global__ __launch_bounds__(256) void k_place(
    const unsigned* __restrict__ pairs, const int* __restrict__ tbase,
    const int* __restrict__ row_ptr, int* __restrict__ srcs, int N)
{
    __shared__ int lrp[64];
    __shared__ int lcur[64];
    int b = blockIdx.x;
    if (threadIdx.x < 64){
        int node = (b << BSHIFT) + threadIdx.x;
        lrp[threadIdx.x] = (node < N) ? row_ptr[node] : 0;
        lcur[threadIdx.x] = 0;
    }
    __syncthreads();
    int pb = tbase[b], pe = tbase[b + 1];
    for (int e = pb + threadIdx.x; e < pe; e += 256){
        unsigned pr = pairs[e];
        int li = pr >> 26;
        int r = atomicAdd(&lcur[li], 1);
        srcs[lrp[li] + r] = (int)(pr & 0x03FFFFFFu);
    }
}

// ============================ row_ptr scan (over deg) ============================

__global__ void k_scan_sums(const int* __restrict__ deg, int* __restrict__ csum, int N){
    __shared__ int sd[256];
    int base = blockIdx.x * 1024;
    int s = 0;
    for (int i = threadIdx.x; i < 1024; i += 256){
        int idx = base + i;
        s += (idx < N) ? deg[idx] : 0;
    }
    sd[threadIdx.x] = s; __syncthreads();
    for (int off = 128; off > 0; off >>= 1){
        if (threadIdx.x < off) sd[threadIdx.x] += sd[threadIdx.x + off];
        __syncthreads();
    }
    if (threadIdx.x == 0) csum[blockIdx.x] = sd[0];
}

__global__ void k_scan_apply(const int* __restrict__ deg, const int* __restrict__ csum,
                             int* __restrict__ row_ptr, int N, int E, int nchunks){
    __shared__ int ts[256];
    __shared__ int base_s;
    int partial = 0;
    for (int j = threadIdx.x; j < nchunks; j += 256)
        if (j < (int)blockIdx.x) partial += csum[j];
    ts[threadIdx.x] = partial; __syncthreads();
    for (int off = 128; off > 0; off >>= 1){
        if (threadIdx.x < off) ts[threadIdx.x] += ts[threadIdx.x + off];
        __syncthreads();
    }
    if (threadIdx.x == 0) base_s = ts[0];
    __syncthreads();
    int blk_base = base_s;
    __syncthreads();   // everyone read base_s; ts about to be reused

    int base = blockIdx.x * 1024 + threadIdx.x * 4;
    int v[4]; int s = 0;
    #pragma unroll
    for (int j = 0; j < 4; ++j){
        int idx = base + j;
        v[j] = (idx < N) ? deg[idx] : 0;
        s += v[j];
    }
    ts[threadIdx.x] = s; __syncthreads();
    #pragma unroll
    for (int off = 1; off < 256; off <<= 1){
        int t = (threadIdx.x >= off) ? ts[threadIdx.x - off] : 0;
        __syncthreads();
        ts[threadIdx.x] += t;
        __syncthreads();
    }
    int excl = ts[threadIdx.x] - s + blk_base;
    #pragma unroll
    for (int j = 0; j < 4; ++j){
        int idx = base + j;
        if (idx < N) row_ptr[idx] = excl;
        excl += v[j];
    }
    if (blockIdx.x == 0 && threadIdx.x == 0) row_ptr[N] = E;
}

// ============================ graph segment starts (binary search) ============================

__global__ void k_gstart_bs(const int* __restrict__ batch, int* __restrict__ gstart,
                            int N, int NG){
    int g = blockIdx.x * blockDim.x + threadIdx.x;
    if (g > NG) return;
    int lo = 0, hi = N;
    while (lo < hi){
        int mid = (lo + hi) >> 1;
        if (batch[mid] < g) lo = mid + 1; else hi = mid;
    }
    gstart[g] = lo;
}

// ============================ packing (fp8) ============================

__global__ void k_pack_w(const float* W0, const float* W1, const float* W2, const float* W3,
                         const float* W4, const float* W5, const float* W6, const float* W7,
                         unsigned char* __restrict__ out){
    const float* Ws[8] = {W0,W1,W2,W3,W4,W5,W6,W7};
    const float* W = Ws[blockIdx.z];
    int lane = threadIdx.x;
    int n  = blockIdx.x * 16 + (lane & 15);
    int k0 = blockIdx.y * 32 + (lane >> 4) * 8;
    float f[8];
    #pragma unroll
    for (int j = 0; j < 8; ++j){
        int k = k0 + j;
        f[j] = (n < 200 && k < 200) ? W[n * 200 + k] : 0.f;
    }
    uint2 u;
    u.x = pk4_fp8(f[0], f[1], f[2], f[3]);
    u.y = pk4_fp8(f[4], f[5], f[6], f[7]);
    size_t off = ((((size_t)blockIdx.z * NT + blockIdx.x) * KS + blockIdx.y) * 64 + lane) * 8;
    *reinterpret_cast<uint2*>(out + off) = u;
}

// combined: pack_x (blocks 0..xblk-1), pack_w1 (next NT blocks), pack_b (next 5)
__global__ __launch_bounds__(256) void k_pack_misc(
    const float* __restrict__ x, unsigned short* __restrict__ xp,
    unsigned char* __restrict__ xa,
    const float* __restrict__ Wl1, const float* __restrict__ Wr1,
    unsigned char* __restrict__ w1pack,
    const float* b0, const float* b1, const float* b2, const float* b3, const float* b4,
    float* __restrict__ biasp, int N, int xblk)
{
    int bid = blockIdx.x;
    if (bid < xblk){
        int i = bid * 256 + threadIdx.x;
        int node = i >> 4, c = i & 15;
        if (node < N){
            float f = (c < 11) ? x[(size_t)node * 11 + c] : 0.f;
            xp[i] = f2bf(f);
            xa[(size_t)node * 32 + 16 + c] = b1_fp8(f);
        }
        return;
    }
    int j = bid - xblk;
    if (j < NT){
        if (threadIdx.x >= 64) return;
        int lane = threadIdx.x;
        int n  = j * 16 + (lane & 15);
        int k0 = (lane >> 4) * 8;
        float f[8];
        #pragma unroll
        for (int jj = 0; jj < 8; ++jj){
            int k = k0 + jj;
            float v = 0.f;
            if (n < 200){
                if (k < 11)                 v = Wl1[n * 11 + k];
                else if (k >= 16 && k < 27) v = Wr1[n * 11 + (k - 16)];
            }
            f[jj] = v;
        }
        uint2 u;
        u.x = pk4_fp8(f[0], f[1], f[2], f[3]);
        u.y = pk4_fp8(f[4], f[5], f[6], f[7]);
        size_t off = ((size_t)j * 64 + lane) * 8;
        *reinterpret_cast<uint2*>(w1pack + off) = u;
        return;
    }
    int l = j - NT;   // 0..4
    const float* bs[5] = {b0,b1,b2,b3,b4};
    int c = threadIdx.x;
    if (c < ROWP) biasp[l * ROWP + c] = (c < 200) ? bs[l][c] : 0.f;
}

// ============================ aggregation (layer 1, K=11) ============================

__global__ __launch_bounds__(256) void k_agg11(
    const unsigned short* __restrict__ xp, const int* __restrict__ row_ptr,
    const int* __restrict__ srcs, const float* __restrict__ inv_deg,
    unsigned char* __restrict__ xa, int N)
{
    int half = threadIdx.x >> 5;              // 0..7
    int node = blockIdx.x * 8 + half;
    int l = threadIdx.x & 31;
    if (node >= N) return;
    int beg = row_ptr[node], end = row_ptr[node + 1];

    float acc[12];
    #pragma unroll
    for (int i = 0; i < 12; ++i) acc[i] = 0.f;

    const uint4* x4 = reinterpret_cast<const uint4*>(xp);
    const uint2* x2 = reinterpret_cast<const uint2*>(xp);
    for (int e = beg + l; e < end; e += 32){
        int sn = srcs[e];
        uint4 a = x4[(size_t)sn * 2];
        uint2 b = x2[(size_t)sn * 4 + 2];
        union { unsigned u; float f; } c;
        c.u = a.x << 16;         acc[0] += c.f;
        c.u = a.x & 0xffff0000u; acc[1] += c.f;
        c.u = a.y << 16;         acc[2] += c.f;
        c.u = a.y & 0xffff0000u; acc[3] += c.f;
        c.u = a.z << 16;         acc[4] += c.f;
        c.u = a.z & 0xffff0000u; acc[5] += c.f;
        c.u = a.w << 16;         acc[6] += c.f;
        c.u = a.w & 0xffff0000u; acc[7] += c.f;
        c.u = b.x << 16;         acc[8] += c.f;
        c.u = b.x & 0xffff0000u; acc[9] += c.f;
        c.u = b.y << 16;         acc[10] += c.f;
        c.u = b.y & 0xffff0000u; acc[11] += c.f;
    }

    #pragma unroll
    for (int i = 0; i < 11; ++i){
        acc[i] += __shfl_xor(acc[i], 1, 64);
        acc[i] += __shfl_xor(acc[i], 2, 64);
        acc[i] += __shfl_xor(acc[i], 4, 64);
        acc[i] += __shfl_xor(acc[i], 8, 64);
        acc[i] += __shfl_xor(acc[i], 16, 64);
    }

    if (l == 0){
        float id = inv_deg[node];
        float v[12];
        #pragma unroll
        for (int i = 0; i < 11; ++i) v[i] = acc[i] * id;
        v[11] = 0.f;
        uint4 o;
        o.x = pk4_fp8(v[0], v[1], v[2], v[3]);
        o.y = pk4_fp8(v[4], v[5], v[6], v[7]);
        o.z = pk4_fp8(v[8], v[9], v[10], v[11]);
        o.w = 0u;
        *reinterpret_cast<uint4*>(xa + (size_t)node * 32) = o;
    }
}

// ============================ gather (layers 2..5) — XCD-pinned slice version ============================
// slice = blockIdx & 7 -> hardware round-robin pins slice s to XCD s; the 3.2 MB
// plane becomes L2-resident there. 2-lane groups, one node per group, serial
// 4-deep edge walk, zero cross-lane reduction.

__device__ __forceinline__ void accum_fp8v(floatx2* a, uint4 u){
    a[0] += __builtin_amdgcn_cvt_pk_f32_fp8((int)u.x, false);
    a[1] += __builtin_amdgcn_cvt_pk_f32_fp8((int)u.x, true );
    a[2] += __builtin_amdgcn_cvt_pk_f32_fp8((int)u.y, false);
    a[3] += __builtin_amdgcn_cvt_pk_f32_fp8((int)u.y, true );
    a[4] += __builtin_amdgcn_cvt_pk_f32_fp8((int)u.z, false);
    a[5] += __builtin_amdgcn_cvt_pk_f32_fp8((int)u.z, true );
    a[6] += __builtin_amdgcn_cvt_pk_f32_fp8((int)u.w, false);
    a[7] += __builtin_amdgcn_cvt_pk_f32_fp8((int)u.w, true );
}

__global__ __launch_bounds__(256) void k_agg200s(
    const unsigned char* __restrict__ hpl, const int* __restrict__ row_ptr,
    const int* __restrict__ srcs, const float* __restrict__ inv_deg,
    unsigned char* __restrict__ aggpl, int N)
{
    const int s    = blockIdx.x & 7;          // slice == XCD (round-robin dispatch)
    const int nb0  = (blockIdx.x >> 3) * 128; // node base for this block
    const int grp  = threadIdx.x >> 1;        // 0..127: one node per 2-lane group
    const int half = threadIdx.x & 1;         // 16-B half of the 32-B slice row
    const int node = nb0 + grp;
    if (node >= N) return;
    const size_t plane = (size_t)N * 32;
    const uint4* h4 = reinterpret_cast<const uint4*>(hpl + (size_t)s * plane);
    int beg = row_ptr[node], end = row_ptr[node + 1];

    floatx2 acc[8];
    #pragma unroll
    for (int i = 0; i < 8; ++i) acc[i] = (floatx2){0.f, 0.f};

    int e = beg;
    for (; e + 4 <= end; e += 4){
        int s0 = srcs[e];
        int s1 = srcs[e + 1];
        int s2 = srcs[e + 2];
        int s3 = srcs[e + 3];
        uint4 u0 = h4[(size_t)s0 * 2 + half];
        uint4 u1 = h4[(size_t)s1 * 2 + half];
        uint4 u2 = h4[(size_t)s2 * 2 + half];
        uint4 u3 = h4[(size_t)s3 * 2 + half];
        accum_fp8v(acc, u0);
        accum_fp8v(acc, u1);
        accum_fp8v(acc, u2);
        accum_fp8v(acc, u3);
    }
    for (; e < end; ++e){
        int s0 = srcs[e];
        uint4 u0 = h4[(size_t)s0 * 2 + half];
        accum_fp8v(acc, u0);
    }

    float id = inv_deg[node];
    uint4 o;
    o.x = pk4_fp8(acc[0][0]*id, acc[0][1]*id, acc[1][0]*id, acc[1][1]*id);
    o.y = pk4_fp8(acc[2][0]*id, acc[2][1]*id, acc[3][0]*id, acc[3][1]*id);
    o.z = pk4_fp8(acc[4][0]*id, acc[4][1]*id, acc[5][0]*id, acc[5][1]*id);
    o.w = pk4_fp8(acc[6][0]*id, acc[6][1]*id, acc[7][0]*id, acc[7][1]*id);
    *reinterpret_cast<uint4*>(aggpl + (size_t)s * plane + (size_t)node * 32 + half * 16) = o;
}

// ============================ layer-1 MFMA + fused pool ============================

__global__ __launch_bounds__(256) void k_layer1_mfma(
    const unsigned char* __restrict__ xa, const unsigned char* __restrict__ W1p,
    const float* __restrict__ biasp, const int* __restrict__ batch,
    float* __restrict__ gsum, unsigned char* __restrict__ outp, int M)
{
    __shared__ __align__(16) unsigned char ptile[64 * PT_STRIDE];
    __shared__ int lb[64];
    const int wave = threadIdx.x >> 6;
    const int lane = threadIdx.x & 63;
    const int n = lane & 15;
    const int q = lane >> 4;
    const int r0 = blockIdx.x * 64;
    const int nrows = (M - r0 < 64) ? (M - r0) : 64;
    int row = r0 + wave * 16 + n;
    int rowc = row < M ? row : (M - 1);

    if (threadIdx.x < 64 && threadIdx.x < nrows) lb[threadIdx.x] = batch[r0 + threadIdx.x];

    long a = *reinterpret_cast<const long*>(xa + (size_t)rowc * 32 + q * 8);

    floatx4 acc[NTC];
    #pragma unroll
    for (int nt = 0; nt < NTC; ++nt){
        long b = *reinterpret_cast<const long*>(W1p + ((size_t)nt * 64 + lane) * 8);
        acc[nt] = __builtin_amdgcn_mfma_f32_16x16x32_fp8_fp8(a, b, (floatx4){0.f,0.f,0.f,0.f}, 0, 0, 0);
    }

    // epilogue -> LDS pool tile
    {
        int lr0 = wave * 16 + q * 4;
        #pragma unroll
        for (int nt = 0; nt < NTC; ++nt){
            float bsv = biasp[nt * 16 + n];
            #pragma unroll
            for (int r = 0; r < 4; ++r){
                float v = fmaxf(acc[nt][r] + bsv, 0.f);
                ptile[(lr0 + r) * PT_STRIDE + nt * 16 + n] = b1_fp8(v);
            }
        }
    }
    __syncthreads();

    // vectorized tile -> global h write (8-plane layout: c -> plane c>>1, half c&1)
    {
        const size_t plane = (size_t)M * 32;
        const uint4* s4 = reinterpret_cast<const uint4*>(ptile);
        int tot = nrows * 13;
        for (int i = threadIdx.x; i < tot; i += 256){
            int r = i / 13, c = i - r * 13;
            unsigned char* dst = outp + (size_t)(c >> 1) * plane
                               + (size_t)(r0 + r) * 32 + (c & 1) * 16;
            *reinterpret_cast<uint4*>(dst) = s4[i];
        }
    }

    // segmented pool reduce (batch sorted -> few segments per block)
    if (threadIdx.x < 50){
        int t = threadIdx.x;
        const unsigned* pd = reinterpret_cast<const unsigned*>(ptile);
        float s0 = 0.f, s1 = 0.f, s2 = 0.f, s3 = 0.f;
        int cur = lb[0];
        for (int r = 0; r < nrows; ++r){
            int gg = lb[r];
            if (gg != cur){
                float* gp = &gsum[(size_t)cur * 1000 + t * 4];
                atomicAdd(gp + 0, s0); atomicAdd(gp + 1, s1);
                atomicAdd(gp + 2, s2); atomicAdd(gp + 3, s3);
                s0 = s1 = s2 = s3 = 0.f;
                cur = gg;
            }
            unsigned u = pd[r * 52 + t];
            floatx2 lo = __builtin_amdgcn_cvt_pk_f32_fp8((int)u, false);
            floatx2 hi = __builtin_amdgcn_cvt_pk_f32_fp8((int)u, true);
            s0 += lo[0]; s1 += lo[1]; s2 += hi[0]; s3 += hi[1];
        }
        float* gp = &gsum[(size_t)cur * 1000 + t * 4];
        atomicAdd(gp + 0, s0); atomicAdd(gp + 1, s1);
        atomicAdd(gp + 2, s2); atomicAdd(gp + 3, s3);
    }
}

// ============================ MFMA SAGE GEMM + fused pool (layers 2..5) ============================
// A rows read from 8-plane layout (K-slice ks == plane ks); lw reused as pool tile.
__global__ __launch_bounds__(256) void k_sage_mfma(
    const unsigned char* __restrict__ Aagg, const unsigned char* __restrict__ Ah,
    const unsigned char* __restrict__ Wlp, const unsigned char* __restrict__ Wrp,
    const float* __restrict__ biasp, const int* __restrict__ batch,
    float* __restrict__ gsum, int col_off,
    unsigned char* __restrict__ outp, int M)
{
    __shared__ __align__(16) unsigned char lw[STAGE_BYTES];   // 45.5 KB (weights, then pool tile)
    __shared__ int lb[64];
    const int wave = threadIdx.x >> 6;
    const int lane = threadIdx.x & 63;
    const int n = lane & 15;
    const int q = lane >> 4;
    const int r0 = blockIdx.x * 64;
    const int nrows = (M - r0 < 64) ? (M - r0) : 64;
    int row = r0 + wave * 16 + n;
    int rowc = row < M ? row : (M - 1);

    if (threadIdx.x < 64 && threadIdx.x < nrows) lb[threadIdx.x] = batch[r0 + threadIdx.x];

    floatx4 acc[NTC];
    #pragma unroll
    for (int nt = 0; nt < NTC; ++nt) acc[nt] = (floatx4){0.f, 0.f, 0.f, 0.f};

    const unsigned char* Wp[2] = {Wlp, Wrp};
    const unsigned char* Ap[2] = {Aagg, Ah};
    const size_t plane = (size_t)M * 32;

    #pragma unroll
    for (int phase = 0; phase < 2; ++phase){
        if (phase) __syncthreads();   // all waves done reading previous phase
        {
            const uint4* src4 = reinterpret_cast<const uint4*>(Wp[phase]);
            uint4* dst4 = reinterpret_cast<uint4*>(lw);
            for (int i = threadIdx.x; i < STAGE_BYTES / 16; i += 256)
                dst4[i] = src4[i];
        }
        __syncthreads();

        const unsigned char* Ab = Ap[phase] + (size_t)rowc * 32 + q * 8;
        long a[KS];
        #pragma unroll
        for (int ks = 0; ks < KS; ++ks)
            a[ks] = *reinterpret_cast<const long*>(Ab + (size_t)ks * plane);

        #pragma unroll
        for (int ks = 0; ks < KS; ++ks){
            #pragma unroll
            for (int nt = 0; nt < NTC; ++nt){
                long b = *reinterpret_cast<const long*>(&lw[((nt * KS + ks) * 64 + lane) * 8]);
                acc[nt] = __builtin_amdgcn_mfma_f32_16x16x32_fp8_fp8(a[ks], b, acc[nt], 0, 0, 0);
            }
        }
    }
    __syncthreads();   // all MFMA done reading lw; reuse as pool tile

    unsigned char* ptile = lw;
    {
        int lr0 = wave * 16 + q * 4;
        #pragma unroll
        for (int nt = 0; nt < NTC; ++nt){
            float bsv = biasp[nt * 16 + n];
            #pragma unroll
            for (int r = 0; r < 4; ++r){
                float v = fmaxf(acc[nt][r] + bsv, 0.f);
                ptile[(lr0 + r) * PT_STRIDE + nt * 16 + n] = b1_fp8(v);
            }
        }
    }
    __syncthreads();   // pool tile complete

    // vectorized tile -> global h write (8-plane layout; pads stay zero from memset)
    {
        const uint4* s4 = reinterpret_cast<const uint4*>(ptile);
        int tot = nrows * 13;
        for (int i = threadIdx.x; i < tot; i += 256){
            int r = i / 13, c = i - r * 13;
            unsigned char* dst = outp + (size_t)(c >> 1) * plane
                               + (size_t)(r0 + r) * 32 + (c & 1) * 16;
            *reinterpret_cast<uint4*>(dst) = s4[i];
        }
    }

    // segmented pool reduce (batch sorted -> few segments per block)
    if (threadIdx.x < 50){
        int t = threadIdx.x;
        const unsigned* pd = reinterpret_cast<const unsigned*>(ptile);
        float s0 = 0.f, s1 = 0.f, s2 = 0.f, s3 = 0.f;
        int cur = lb[0];
        for (int r = 0; r < nrows; ++r){
            int gg = lb[r];
            if (gg != cur){
                float* gp = &gsum[(size_t)cur * 1000 + col_off + t * 4];
                atomicAdd(gp + 0, s0); atomicAdd(gp + 1, s1);
                atomicAdd(gp + 2, s2); atomicAdd(gp + 3, s3);
                s0 = s1 = s2 = s3 = 0.f;
                cur = gg;
            }
            unsigned u = pd[r * 52 + t];
            floatx2 lo = __builtin_amdgcn_cvt_pk_f32_fp8((int)u, false);
            floatx2 hi = __builtin_amdgcn_cvt_pk_f32_fp8((int)u, true);
            s0 += lo[0]; s1 += lo[1]; s2 += hi[0]; s3 += hi[1];
        }
        float* gp = &gsum[(size_t)cur * 1000 + col_off + t * 4];
        atomicAdd(gp + 0, s0); atomicAdd(gp + 1, s1);
        atomicAdd(gp + 2, s2); atomicAdd(gp + 3, s3);
    }
}

// ============================ MLP head (fp32) ============================

__global__ __launch_bounds__(256) void k_mlp_first(
    const float* __restrict__ gsum, const int* __restrict__ gstart,
    const float* __restrict__ W, const float* __restrict__ b,
    float* __restrict__ outp)
{
    __shared__ __align__(16) float row[1000];
    int g = blockIdx.x;
    int cnt = gstart[g+1] - gstart[g];
    float inv = 1.0f / fmaxf((float)cnt, 1.0f);
    for (int i = threadIdx.x; i < 1000; i += 256)
        row[i] = gsum[(size_t)g * 1000 + i] * inv;
    __syncthreads();
    for (int c = threadIdx.x; c < 500; c += 256){
        const float4* w4 = reinterpret_cast<const float4*>(W + (size_t)c * 1000);
        const float4* r4 = reinterpret_cast<const float4*>(row);
        float s = b[c];
        for (int k = 0; k < 250; ++k){
            float4 wv = w4[k]; float4 rv = r4[k];
            s = fmaf(wv.x, rv.x, s);
            s = fmaf(wv.y, rv.y, s);
            s = fmaf(wv.z, rv.z, s);
            s = fmaf(wv.w, rv.w, s);
        }
        outp[(size_t)g * 500 + c] = s;
    }
}

__global__ __launch_bounds__(256) void k_mlp23(
    const float* __restrict__ t1, const float* __restrict__ W2,
    const float* __restrict__ b2, const float* __restrict__ W3,
    const float* __restrict__ b3, float* __restrict__ outp)
{
    __shared__ __align__(16) float row[500];
    __shared__ float red[256];
    int g = blockIdx.x;
    for (int i = threadIdx.x; i < 500; i += 256) row[i] = t1[(size_t)g * 500 + i];
    __syncthreads();
    float prod = 0.f;
    int c = threadIdx.x;
    if (c < 250){
        const float4* w4 = reinterpret_cast<const float4*>(W2 + (size_t)c * 500);
        const float4* r4 = reinterpret_cast<const float4*>(row);
        float s = b2[c];
        for (int k = 0; k < 125; ++k){
            float4 wv = w4[k]; float4 rv = r4[k];
            s = fmaf(wv.x, rv.x, s);
            s = fmaf(wv.y, rv.y, s);
            s = fmaf(wv.z, rv.z, s);
            s = fmaf(wv.w, rv.w, s);
        }
        prod = s * W3[c];
    }
    red[threadIdx.x] = prod;
    __syncthreads();
    for (int off = 128; off > 0; off >>= 1){
        if (threadIdx.x < off) red[threadIdx.x] += red[threadIdx.x + off];
        __syncthreads();
    }
    if (threadIdx.x == 0)
        outp[g] = 1.0f / (1.0f + expf(-(red[0] + b3[0])));
}

// ============================ launch ============================

extern "C" void kernel_launch(void* const* d_in, const int* in_sizes, int n_in,
                              void* d_out, int out_size, void* d_ws, size_t ws_size,
                              hipStream_t stream)
{
    const float* x    = (const float*)d_in[0];
    const int*   ei   = (const int*)d_in[1];
    const int*   batch= (const int*)d_in[2];
    const float* Wl[5]; const float* bl[5]; const float* Wr[5];
    for (int i = 0; i < 5; ++i){
        Wl[i] = (const float*)d_in[3 + 3*i];
        bl[i] = (const float*)d_in[4 + 3*i];
        Wr[i] = (const float*)d_in[5 + 3*i];
    }
    const float* pw1 = (const float*)d_in[18]; const float* pb1 = (const float*)d_in[19];
    const float* pw2 = (const float*)d_in[20]; const float* pb2 = (const float*)d_in[21];
    const float* pw3 = (const float*)d_in[22]; const float* pb3 = (const float*)d_in[23];
    float* out = (float*)d_out;

    const int N  = in_sizes[2];
    const int E  = in_sizes[1] / 2;
    const int NG = out_size;
    const int* esrc = ei;
    const int* edst = ei + E;
    const int nbuck = (N + 63) >> BSHIFT;          // 1563
    const int nblk  = (E + EPB - 1) / EPB;         // 782

    // ---- workspace carve ----
    char* p = (char*)d_ws;
    auto carve = [&](size_t bytes)->void* {
        void* r = (void*)p;
        p += (bytes + 255) & ~(size_t)255;
        return r;
    };
    int*   deg     = (int*)  carve((size_t)N * 4);
    int*   row_ptr = (int*)  carve(((size_t)N + 1) * 4);
    int*   csum    = (int*)  carve(4096);
    int*   hist    = (int*)  carve((size_t)nblk * nbuck * 4);
    int*   Tb      = (int*)  carve((size_t)nbuck * 4);
    int*   tbase   = (int*)  carve(((size_t)nbuck + 1) * 4);
    float* invdeg  = (float*)carve((size_t)N * 4);
    int*   gstart  = (int*)  carve(((size_t)NG + 1) * 4);
    int*   srcs    = (int*)  carve((size_t)E * 4);
    unsigned* pairs = (unsigned*)carve((size_t)E * 4);
    unsigned short* xp    = (unsigned short*)carve((size_t)N * 16 * 2);
    unsigned char*  xa    = (unsigned char*) carve((size_t)N * 32);
    unsigned char*  agg8  = (unsigned char*) carve((size_t)N * ROWP);   // 8 planes
    unsigned char*  h8A   = (unsigned char*) carve((size_t)N * ROWP);   // 8 planes
    unsigned char*  h8B   = (unsigned char*) carve((size_t)N * ROWP);   // 8 planes
    unsigned char*  wpack = (unsigned char*) carve((size_t)8 * PACK_BYTES);
    unsigned char*  w1pack= (unsigned char*) carve((size_t)PACK1_BYTES);
    float* biasp   = (float*)carve((size_t)5 * ROWP * 4);
    float* gsum    = (float*)carve((size_t)NG * 1000 * 4);
    float* t1      = (float*)carve((size_t)NG * 500 * 4);

    // ---- zero what must be zero ----
    hipMemsetAsync(gsum, 0, (size_t)NG * 1000 * 4, stream);
    // h pad planes/cols must stay zero across all layers
    hipMemsetAsync(h8A, 0, (size_t)N * ROWP, stream);
    hipMemsetAsync(h8B, 0, (size_t)N * ROWP, stream);

    // ---- packing ----
    int xblk = (N * 16 + 255) / 256;
    k_pack_w<<<dim3(NT, KS, 8), 64, 0, stream>>>(
        Wl[1], Wr[1], Wl[2], Wr[2], Wl[3], Wr[3], Wl[4], Wr[4], wpack);
    k_pack_misc<<<xblk + NT + 5, 256, 0, stream>>>(
        x, xp, xa, Wl[0], Wr[0], w1pack,
        bl[0], bl[1], bl[2], bl[3], bl[4], biasp, N, xblk);

    // ---- binned CSR build (no hot global atomics) ----
    k_bin_hist<<<nblk, 256, 0, stream>>>(edst, hist, E, nbuck);
    k_col_scan<<<(nbuck + 63) / 64, 256, 0, stream>>>(hist, Tb, nblk, nbuck);
    k_scan_t<<<1, 256, 0, stream>>>(Tb, tbase, nbuck);
    k_bin_scatter<<<nblk, 256, 0, stream>>>(esrc, edst, hist, tbase, pairs, E, nbuck);
    k_bucket_deg<<<nbuck, 256, 0, stream>>>(pairs, tbase, deg, invdeg, N);
    int nchunks = (N + 1023) / 1024;
    k_scan_sums<<<nchunks, 256, 0, stream>>>(deg, csum, N);
    k_scan_apply<<<nchunks, 256, 0, stream>>>(deg, csum, row_ptr, N, E, nchunks);
    k_place<<<nbuck, 256, 0, stream>>>(pairs, tbase, row_ptr, srcs, N);

    // ---- graph starts (binary search over sorted batch) ----
    k_gstart_bs<<<(NG + 256) / 256, 256, 0, stream>>>(batch, gstart, N, NG);

    // ---- layer 1 (fp8 MFMA over K=32 = [agg11 | x11]) + fused pool ----
    int gb = (N + 63) / 64;
    k_agg11<<<(N + 7) / 8, 256, 0, stream>>>(xp, row_ptr, srcs, invdeg, xa, N);
    k_layer1_mfma<<<gb, 256, 0, stream>>>(xa, w1pack, biasp, batch, gsum, h8A, N);

    // ---- layers 2..5 (XCD-pinned slice gather + fp8 MFMA + fused pool) ----
    unsigned char* hc = h8A; unsigned char* hn = h8B;
    int gs = ((N + 127) / 128) * 8;
    for (int L = 1; L < 5; ++L){
        k_agg200s<<<gs, 256, 0, stream>>>(hc, row_ptr, srcs, invdeg, agg8, N);
        const unsigned char* Wlp = wpack + (size_t)((L-1)*2 + 0) * PACK_BYTES;
        const unsigned char* Wrp = wpack + (size_t)((L-1)*2 + 1) * PACK_BYTES;
        k_sage_mfma<<<gb, 256, 0, stream>>>(agg8, hc, Wlp, Wrp,
                                            biasp + L * ROWP, batch, gsum, 200 * L,
                                            hn, N);
        unsigned char* t = hc; hc = hn; hn = t;
    }

    // ---- MLP head (pool finalize fused into first layer) ----
    k_mlp_first<<<NG, 256, 0, stream>>>(gsum, gstart, pw1, pb1, t1);
    k_mlp23<<<NG, 256, 0, stream>>>(t1, pw2, pb2, pw3, pb3, out);
}

// Round 8
// 1078.182 us; speedup vs baseline: 1.2882x; 1.2651x over previous
//
#include <hip/hip_runtime.h>
#include <math.h>

typedef __attribute__((ext_vector_type(4))) float floatx4;
typedef __attribute__((ext_vector_type(2))) float floatx2;

#define ROWP 256          // padded row length (fp8 bytes): 16 x 16 (2 x 128-B sectors, aligned)
#define R4   16           // uint4 per row
#define NT 14             // packed weight col-tiles (layout)
#define NTC 13            // used col-tiles (13 x 16 = 208 cols; 200 real)
#define KS 7              // 7 x 32 = 224 K (200 real + pad)
#define PACK_BYTES (NT*KS*64*8)   // bytes per packed fp8 weight matrix (layers 2..5)
#define PACK1_BYTES (NT*64*8)     // layer-1 packed fp8 weight (K=32)
#define STAGE_BYTES (NTC*KS*64*8) // 46592 B staged per phase in sage
#define BSHIFT 6          // 64 nodes per CSR bucket
#define EPB 8192          // edges per binning block (8192 halves hist vs 4096)
#define MAXBUCK 1600      // LDS capacity for bucket arrays (>= nbuck=1563)
#define PT_STRIDE 208     // fp8 bytes per pool-tile row (13 uint4)

__device__ __forceinline__ unsigned short f2bf(float f){
    union { float f; unsigned u; } v; v.f = f;
    unsigned r = v.u + 0x7FFF + ((v.u >> 16) & 1);
    return (unsigned short)(r >> 16);
}
__device__ __forceinline__ unsigned pk4_fp8(float a, float b, float c, float d){
    int w = __builtin_amdgcn_cvt_pk_fp8_f32(a, b, 0, false);
    w = __builtin_amdgcn_cvt_pk_fp8_f32(c, d, w, true);
    return (unsigned)w;
}
__device__ __forceinline__ unsigned char b1_fp8(float a){
    int w = __builtin_amdgcn_cvt_pk_fp8_f32(a, a, 0, false);
    return (unsigned char)(w & 0xFF);
}

// ============================ binned CSR build (no hot global atomics) ============================

__global__ __launch_bounds__(256) void k_bin_hist(
    const int* __restrict__ dst, int* __restrict__ hist, int E, int nbuck)
{
    __shared__ int lh[MAXBUCK];
    for (int i = threadIdx.x; i < nbuck; i += 256) lh[i] = 0;
    __syncthreads();
    int base = blockIdx.x * EPB;
    #pragma unroll
    for (int k = 0; k < EPB / 256; ++k){
        int e = base + k * 256 + threadIdx.x;
        if (e < E) atomicAdd(&lh[dst[e] >> BSHIFT], 1);
    }
    __syncthreads();
    for (int i = threadIdx.x; i < nbuck; i += 256)
        hist[(size_t)blockIdx.x * nbuck + i] = lh[i];
}

__global__ __launch_bounds__(256) void k_col_scan(
    int* __restrict__ hist, int* __restrict__ T, int nblk, int nbuck)
{
    __shared__ int part[4][64];
    int w = threadIdx.x >> 6, l = threadIdx.x & 63;
    int b = blockIdx.x * 64 + l;
    int chunk = (nblk + 3) >> 2;
    int j0 = w * chunk, j1 = j0 + chunk; if (j1 > nblk) j1 = nblk;
    int s = 0;
    if (b < nbuck)
        for (int j = j0; j < j1; ++j) s += hist[(size_t)j * nbuck + b];
    part[w][l] = s;
    __syncthreads();
    if (b < nbuck){
        int run = 0;
        for (int w2 = 0; w2 < w; ++w2) run += part[w2][l];
        for (int j = j0; j < j1; ++j){
            int v = hist[(size_t)j * nbuck + b];
            hist[(size_t)j * nbuck + b] = run;
            run += v;
        }
        if (w == 3) T[b] = part[0][l] + part[1][l] + part[2][l] + part[3][l];
    }
}

// scan over bucket totals + graph-segment starts (fused: spare capacity in the
// 1-block kernel; batch is sorted so gstart[g] = lower_bound(batch, g))
__global__ __launch_bounds__(256) void k_scan_t(
    const int* __restrict__ T, int* __restrict__ tbase, int nbuck,
    const int* __restrict__ batch, int* __restrict__ gstart, int N, int NG)
{
    __shared__ int ts[256];
    int t = threadIdx.x;
    int v[8]; int s = 0;
    int base = t * 8;
    #pragma unroll
    for (int k = 0; k < 8; ++k){
        int idx = base + k;
        v[k] = (idx < nbuck) ? T[idx] : 0;
        s += v[k];
    }
    ts[t] = s; __syncthreads();
    #pragma unroll
    for (int off = 1; off < 256; off <<= 1){
        int p = (t >= off) ? ts[t - off] : 0;
        __syncthreads();
        ts[t] += p;
        __syncthreads();
    }
    int run = ts[t] - s;
    #pragma unroll
    for (int k = 0; k < 8; ++k){
        int idx = base + k;
        if (idx < nbuck) tbase[idx] = run;
        run += v[k];
    }
    if (t == 255) tbase[nbuck] = ts[255];

    // fused gstart (independent of scan state)
    for (int g = t; g <= NG; g += 256){
        int lo = 0, hi = N;
        while (lo < hi){
            int mid = (lo + hi) >> 1;
            if (batch[mid] < g) lo = mid + 1; else hi = mid;
        }
        gstart[g] = lo;
    }
}

// pairs packed into 4 B: (dst&63) << 26 | src   (src < 2^26)
__global__ __launch_bounds__(256) void k_bin_scatter(
    const int* __restrict__ src, const int* __restrict__ dst,
    const int* __restrict__ off, const int* __restrict__ tbase,
    unsigned* __restrict__ pairs, int E, int nbuck)
{
    __shared__ int lbase[MAXBUCK];
    __shared__ int lc[MAXBUCK];
    for (int i = threadIdx.x; i < nbuck; i += 256){
        lbase[i] = off[(size_t)blockIdx.x * nbuck + i] + tbase[i];
        lc[i] = 0;
    }
    __syncthreads();
    int base = blockIdx.x * EPB;
    #pragma unroll
    for (int k = 0; k < EPB / 256; ++k){
        int e = base + k * 256 + threadIdx.x;
        if (e < E){
            int d = dst[e];
            int b = d >> BSHIFT;
            int r = atomicAdd(&lc[b], 1);
            pairs[lbase[b] + r] = ((unsigned)(d & 63) << 26) | (unsigned)src[e];
        }
    }
}

// bucket degree count + inv_deg (fused)
__global__ __launch_bounds__(256) void k_bucket_deg(
    const unsigned* __restrict__ pairs, const int* __restrict__ tbase,
    int* __restrict__ deg, float* __restrict__ inv_deg, int N)
{
    __shared__ int ld[64];
    int b = blockIdx.x;
    if (threadIdx.x < 64) ld[threadIdx.x] = 0;
    __syncthreads();
    int pb = tbase[b], pe = tbase[b + 1];
    for (int e = pb + threadIdx.x; e < pe; e += 256)
        atomicAdd(&ld[pairs[e] >> 26], 1);
    __syncthreads();
    if (threadIdx.x < 64){
        int node = (b << BSHIFT) + threadIdx.x;
        if (node < N){
            int d = ld[threadIdx.x];
            deg[node] = d;
            inv_deg[node] = 1.0f / fmaxf((float)d, 1.0f);
        }
    }
}

__global__ __launch_bounds__(256) void k_place(
    const unsigned* __restrict__ pairs, const int* __restrict__ tbase,
    const int* __restrict__ row_ptr, int* __restrict__ srcs, int N)
{
    __shared__ int lrp[64];
    __shared__ int lcur[64];
    int b = blockIdx.x;
    if (threadIdx.x < 64){
        int node = (b << BSHIFT) + threadIdx.x;
        lrp[threadIdx.x] = (node < N) ? row_ptr[node] : 0;
        lcur[threadIdx.x] = 0;
    }
    __syncthreads();
    int pb = tbase[b], pe = tbase[b + 1];
    for (int e = pb + threadIdx.x; e < pe; e += 256){
        unsigned pr = pairs[e];
        int li = pr >> 26;
        int r = atomicAdd(&lcur[li], 1);
        srcs[lrp[li] + r] = (int)(pr & 0x03FFFFFFu);
    }
}

// ============================ row_ptr scan (over deg) ============================

__global__ void k_scan_sums(const int* __restrict__ deg, int* __restrict__ csum, int N){
    __shared__ int sd[256];
    int base = blockIdx.x * 1024;
    int s = 0;
    for (int i = threadIdx.x; i < 1024; i += 256){
        int idx = base + i;
        s += (idx < N) ? deg[idx] : 0;
    }
    sd[threadIdx.x] = s; __syncthreads();
    for (int off = 128; off > 0; off >>= 1){
        if (threadIdx.x < off) sd[threadIdx.x] += sd[threadIdx.x + off];
        __syncthreads();
    }
    if (threadIdx.x == 0) csum[blockIdx.x] = sd[0];
}

__global__ void k_scan_apply(const int* __restrict__ deg, const int* __restrict__ csum,
                             int* __restrict__ row_ptr, int N, int E, int nchunks){
    __shared__ int ts[256];
    __shared__ int base_s;
    int partial = 0;
    for (int j = threadIdx.x; j < nchunks; j += 256)
        if (j < (int)blockIdx.x) partial += csum[j];
    ts[threadIdx.x] = partial; __syncthreads();
    for (int off = 128; off > 0; off >>= 1){
        if (threadIdx.x < off) ts[threadIdx.x] += ts[threadIdx.x + off];
        __syncthreads();
    }
    if (threadIdx.x == 0) base_s = ts[0];
    __syncthreads();
    int blk_base = base_s;
    __syncthreads();   // everyone read base_s; ts about to be reused

    int base = blockIdx.x * 1024 + threadIdx.x * 4;
    int v[4]; int s = 0;
    #pragma unroll
    for (int j = 0; j < 4; ++j){
        int idx = base + j;
        v[j] = (idx < N) ? deg[idx] : 0;
        s += v[j];
    }
    ts[threadIdx.x] = s; __syncthreads();
    #pragma unroll
    for (int off = 1; off < 256; off <<= 1){
        int t = (threadIdx.x >= off) ? ts[threadIdx.x - off] : 0;
        __syncthreads();
        ts[threadIdx.x] += t;
        __syncthreads();
    }
    int excl = ts[threadIdx.x] - s + blk_base;
    #pragma unroll
    for (int j = 0; j < 4; ++j){
        int idx = base + j;
        if (idx < N) row_ptr[idx] = excl;
        excl += v[j];
    }
    if (blockIdx.x == 0 && threadIdx.x == 0) row_ptr[N] = E;
}

// ============================ packing (fp8) ============================

__global__ void k_pack_w(const float* W0, const float* W1, const float* W2, const float* W3,
                         const float* W4, const float* W5, const float* W6, const float* W7,
                         unsigned char* __restrict__ out){
    const float* Ws[8] = {W0,W1,W2,W3,W4,W5,W6,W7};
    const float* W = Ws[blockIdx.z];
    int lane = threadIdx.x;
    int n  = blockIdx.x * 16 + (lane & 15);
    int k0 = blockIdx.y * 32 + (lane >> 4) * 8;
    float f[8];
    #pragma unroll
    for (int j = 0; j < 8; ++j){
        int k = k0 + j;
        f[j] = (n < 200 && k < 200) ? W[n * 200 + k] : 0.f;
    }
    uint2 u;
    u.x = pk4_fp8(f[0], f[1], f[2], f[3]);
    u.y = pk4_fp8(f[4], f[5], f[6], f[7]);
    size_t off = ((((size_t)blockIdx.z * NT + blockIdx.x) * KS + blockIdx.y) * 64 + lane) * 8;
    *reinterpret_cast<uint2*>(out + off) = u;
}

// combined: pack_x (blocks 0..xblk-1), pack_w1 (next NT blocks), pack_b (next 5)
__global__ __launch_bounds__(256) void k_pack_misc(
    const float* __restrict__ x, unsigned short* __restrict__ xp,
    unsigned char* __restrict__ xa,
    const float* __restrict__ Wl1, const float* __restrict__ Wr1,
    unsigned char* __restrict__ w1pack,
    const float* b0, const float* b1, const float* b2, const float* b3, const float* b4,
    float* __restrict__ biasp, int N, int xblk)
{
    int bid = blockIdx.x;
    if (bid < xblk){
        int i = bid * 256 + threadIdx.x;
        int node = i >> 4, c = i & 15;
        if (node < N){
            float f = (c < 11) ? x[(size_t)node * 11 + c] : 0.f;
            xp[i] = f2bf(f);
            xa[(size_t)node * 32 + 16 + c] = b1_fp8(f);
        }
        return;
    }
    int j = bid - xblk;
    if (j < NT){
        if (threadIdx.x >= 64) return;
        int lane = threadIdx.x;
        int n  = j * 16 + (lane & 15);
        int k0 = (lane >> 4) * 8;
        float f[8];
        #pragma unroll
        for (int jj = 0; jj < 8; ++jj){
            int k = k0 + jj;
            float v = 0.f;
            if (n < 200){
                if (k < 11)                 v = Wl1[n * 11 + k];
                else if (k >= 16 && k < 27) v = Wr1[n * 11 + (k - 16)];
            }
            f[jj] = v;
        }
        uint2 u;
        u.x = pk4_fp8(f[0], f[1], f[2], f[3]);
        u.y = pk4_fp8(f[4], f[5], f[6], f[7]);
        size_t off = ((size_t)j * 64 + lane) * 8;
        *reinterpret_cast<uint2*>(w1pack + off) = u;
        return;
    }
    int l = j - NT;   // 0..4
    const float* bs[5] = {b0,b1,b2,b3,b4};
    int c = threadIdx.x;
    if (c < ROWP) biasp[l * ROWP + c] = (c < 200) ? bs[l][c] : 0.f;
}

// ============================ aggregation (layer 1, K=11) ============================

__global__ __launch_bounds__(256) void k_agg11(
    const unsigned short* __restrict__ xp, const int* __restrict__ row_ptr,
    const int* __restrict__ srcs, const float* __restrict__ inv_deg,
    unsigned char* __restrict__ xa, int N)
{
    int half = threadIdx.x >> 5;              // 0..7
    int node = blockIdx.x * 8 + half;
    int l = threadIdx.x & 31;
    if (node >= N) return;
    int beg = row_ptr[node], end = row_ptr[node + 1];

    float acc[12];
    #pragma unroll
    for (int i = 0; i < 12; ++i) acc[i] = 0.f;

    const uint4* x4 = reinterpret_cast<const uint4*>(xp);
    const uint2* x2 = reinterpret_cast<const uint2*>(xp);
    for (int e = beg + l; e < end; e += 32){
        int sn = srcs[e];
        uint4 a = x4[(size_t)sn * 2];
        uint2 b = x2[(size_t)sn * 4 + 2];
        union { unsigned u; float f; } c;
        c.u = a.x << 16;         acc[0] += c.f;
        c.u = a.x & 0xffff0000u; acc[1] += c.f;
        c.u = a.y << 16;         acc[2] += c.f;
        c.u = a.y & 0xffff0000u; acc[3] += c.f;
        c.u = a.z << 16;         acc[4] += c.f;
        c.u = a.z & 0xffff0000u; acc[5] += c.f;
        c.u = a.w << 16;         acc[6] += c.f;
        c.u = a.w & 0xffff0000u; acc[7] += c.f;
        c.u = b.x << 16;         acc[8] += c.f;
        c.u = b.x & 0xffff0000u; acc[9] += c.f;
        c.u = b.y << 16;         acc[10] += c.f;
        c.u = b.y & 0xffff0000u; acc[11] += c.f;
    }

    #pragma unroll
    for (int i = 0; i < 11; ++i){
        acc[i] += __shfl_xor(acc[i], 1, 64);
        acc[i] += __shfl_xor(acc[i], 2, 64);
        acc[i] += __shfl_xor(acc[i], 4, 64);
        acc[i] += __shfl_xor(acc[i], 8, 64);
        acc[i] += __shfl_xor(acc[i], 16, 64);
    }

    if (l == 0){
        float id = inv_deg[node];
        float v[12];
        #pragma unroll
        for (int i = 0; i < 11; ++i) v[i] = acc[i] * id;
        v[11] = 0.f;
        uint4 o;
        o.x = pk4_fp8(v[0], v[1], v[2], v[3]);
        o.y = pk4_fp8(v[4], v[5], v[6], v[7]);
        o.z = pk4_fp8(v[8], v[9], v[10], v[11]);
        o.w = 0u;
        *reinterpret_cast<uint4*>(xa + (size_t)node * 32) = o;
    }
}

// ============================ gather (layers 2..5) — PROVEN ~116 µs floor, do not restructure ============================

__device__ __forceinline__ void accum_fp8v(floatx2* a, uint4 u){
    a[0] += __builtin_amdgcn_cvt_pk_f32_fp8((int)u.x, false);
    a[1] += __builtin_amdgcn_cvt_pk_f32_fp8((int)u.x, true );
    a[2] += __builtin_amdgcn_cvt_pk_f32_fp8((int)u.y, false);
    a[3] += __builtin_amdgcn_cvt_pk_f32_fp8((int)u.y, true );
    a[4] += __builtin_amdgcn_cvt_pk_f32_fp8((int)u.z, false);
    a[5] += __builtin_amdgcn_cvt_pk_f32_fp8((int)u.z, true );
    a[6] += __builtin_amdgcn_cvt_pk_f32_fp8((int)u.w, false);
    a[7] += __builtin_amdgcn_cvt_pk_f32_fp8((int)u.w, true );
}

__global__ __launch_bounds__(256) void k_agg200(
    const unsigned char* __restrict__ h8, const int* __restrict__ row_ptr,
    const int* __restrict__ srcs, const float* __restrict__ inv_deg,
    unsigned char* __restrict__ agg, int N)
{
    int node = blockIdx.x * 4 + (threadIdx.x >> 6);
    int lane = threadIdx.x & 63;
    if (node >= N) return;
    int g = lane >> 4;    // group 0..3
    int l = lane & 15;    // lane-in-group (all 16 active: 16 x 16 B = 256 B row)
    int beg = row_ptr[node], end = row_ptr[node + 1];
    int nb = end - beg;

    floatx2 acc[8];
    #pragma unroll
    for (int i = 0; i < 8; ++i) acc[i] = (floatx2){0.f, 0.f};

    const uint4* h4 = reinterpret_cast<const uint4*>(h8);

    for (int t = 0; t < nb; t += 64){
        int cnt = nb - t; if (cnt > 64) cnt = 64;
        // one coalesced load of up to 64 src indices for this node
        int eidx = t + lane;
        int si = srcs[beg + (eidx < nb ? eidx : nb - 1)];
        // group g handles batch-local edges j = g, g+4, g+8, ...  (j < cnt)
        int jmax = (cnt - g + 3) >> 2;     // >= 0 since cnt >= 1, g <= 3

        int j = 0;
        for (; j + 4 <= jmax; j += 4){
            int b0 = g + 4 * j;
            int s0 = __shfl(si, b0,      64);
            int s1 = __shfl(si, b0 + 4,  64);
            int s2 = __shfl(si, b0 + 8,  64);
            int s3 = __shfl(si, b0 + 12, 64);
            uint4 u0 = h4[(size_t)s0 * R4 + l];
            uint4 u1 = h4[(size_t)s1 * R4 + l];
            uint4 u2 = h4[(size_t)s2 * R4 + l];
            uint4 u3 = h4[(size_t)s3 * R4 + l];
            accum_fp8v(acc, u0);
            accum_fp8v(acc, u1);
            accum_fp8v(acc, u2);
            accum_fp8v(acc, u3);
        }
        for (; j < jmax; ++j){
            int s0 = __shfl(si, g + 4 * j, 64);
            uint4 u0 = h4[(size_t)s0 * R4 + l];
            accum_fp8v(acc, u0);
        }
    }

    float af[16];
    #pragma unroll
    for (int i = 0; i < 8; ++i){ af[2*i] = acc[i][0]; af[2*i+1] = acc[i][1]; }
    #pragma unroll
    for (int i = 0; i < 16; ++i){
        af[i] += __shfl_xor(af[i], 32, 64);
        af[i] += __shfl_xor(af[i], 16, 64);
    }

    if (g == 0){
        float id = inv_deg[node];
        uint4 o;
        o.x = pk4_fp8(af[0] * id,  af[1] * id,  af[2] * id,  af[3] * id);
        o.y = pk4_fp8(af[4] * id,  af[5] * id,  af[6] * id,  af[7] * id);
        o.z = pk4_fp8(af[8] * id,  af[9] * id,  af[10] * id, af[11] * id);
        o.w = pk4_fp8(af[12] * id, af[13] * id, af[14] * id, af[15] * id);
        *reinterpret_cast<uint4*>(agg + (size_t)node * ROWP + l * 16) = o;
    }
}

// ============================ layer-1 MFMA + fused pool ============================

__global__ __launch_bounds__(256) void k_layer1_mfma(
    const unsigned char* __restrict__ xa, const unsigned char* __restrict__ W1p,
    const float* __restrict__ biasp, const int* __restrict__ batch,
    float* __restrict__ gsum, unsigned char* __restrict__ outp, int M)
{
    __shared__ __align__(16) unsigned char ptile[64 * PT_STRIDE];
    __shared__ int lb[64];
    const int wave = threadIdx.x >> 6;
    const int lane = threadIdx.x & 63;
    const int n = lane & 15;
    const int q = lane >> 4;
    const int r0 = blockIdx.x * 64;
    const int nrows = (M - r0 < 64) ? (M - r0) : 64;
    int row = r0 + wave * 16 + n;
    int rowc = row < M ? row : (M - 1);

    if (threadIdx.x < 64 && threadIdx.x < nrows) lb[threadIdx.x] = batch[r0 + threadIdx.x];

    long a = *reinterpret_cast<const long*>(xa + (size_t)rowc * 32 + q * 8);

    floatx4 acc[NTC];
    #pragma unroll
    for (int nt = 0; nt < NTC; ++nt){
        long b = *reinterpret_cast<const long*>(W1p + ((size_t)nt * 64 + lane) * 8);
        acc[nt] = __builtin_amdgcn_mfma_f32_16x16x32_fp8_fp8(a, b, (floatx4){0.f,0.f,0.f,0.f}, 0, 0, 0);
    }

    // epilogue -> LDS pool tile
    {
        int lr0 = wave * 16 + q * 4;
        #pragma unroll
        for (int nt = 0; nt < NTC; ++nt){
            float bsv = biasp[nt * 16 + n];
            #pragma unroll
            for (int r = 0; r < 4; ++r){
                float v = fmaxf(acc[nt][r] + bsv, 0.f);
                ptile[(lr0 + r) * PT_STRIDE + nt * 16 + n] = b1_fp8(v);
            }
        }
    }
    __syncthreads();

    // vectorized tile -> global h write
    {
        const uint4* s4 = reinterpret_cast<const uint4*>(ptile);
        int tot = nrows * 13;
        for (int i = threadIdx.x; i < tot; i += 256){
            int r = i / 13, c = i - r * 13;
            *reinterpret_cast<uint4*>(outp + (size_t)(r0 + r) * ROWP + c * 16) = s4[i];
        }
    }

    // segmented pool reduce (batch sorted -> few segments per block)
    if (threadIdx.x < 50){
        int t = threadIdx.x;
        const unsigned* pd = reinterpret_cast<const unsigned*>(ptile);
        float s0 = 0.f, s1 = 0.f, s2 = 0.f, s3 = 0.f;
        int cur = lb[0];
        for (int r = 0; r < nrows; ++r){
            int gg = lb[r];
            if (gg != cur){
                float* gp = &gsum[(size_t)cur * 1000 + t * 4];
                atomicAdd(gp + 0, s0); atomicAdd(gp + 1, s1);
                atomicAdd(gp + 2, s2); atomicAdd(gp + 3, s3);
                s0 = s1 = s2 = s3 = 0.f;
                cur = gg;
            }
            unsigned u = pd[r * 52 + t];
            floatx2 lo = __builtin_amdgcn_cvt_pk_f32_fp8((int)u, false);
            floatx2 hi = __builtin_amdgcn_cvt_pk_f32_fp8((int)u, true);
            s0 += lo[0]; s1 += lo[1]; s2 += hi[0]; s3 += hi[1];
        }
        float* gp = &gsum[(size_t)cur * 1000 + t * 4];
        atomicAdd(gp + 0, s0); atomicAdd(gp + 1, s1);
        atomicAdd(gp + 2, s2); atomicAdd(gp + 3, s3);
    }
}

// ============================ MFMA SAGE GEMM + fused pool (layers 2..5) ============================
// Whole-phase LDS weight staging (45.5 KB); A-row loads hoisted ABOVE staging
// so global latency hides under the staging loop. lw reused as pool tile.
__global__ __launch_bounds__(256) void k_sage_mfma(
    const unsigned char* __restrict__ Aagg, const unsigned char* __restrict__ Ah,
    const unsigned char* __restrict__ Wlp, const unsigned char* __restrict__ Wrp,
    const float* __restrict__ biasp, const int* __restrict__ batch,
    float* __restrict__ gsum, int col_off,
    unsigned char* __restrict__ outp, int M)
{
    __shared__ __align__(16) unsigned char lw[STAGE_BYTES];   // 45.5 KB (weights, then pool tile)
    __shared__ int lb[64];
    const int wave = threadIdx.x >> 6;
    const int lane = threadIdx.x & 63;
    const int n = lane & 15;
    const int q = lane >> 4;
    const int r0 = blockIdx.x * 64;
    const int nrows = (M - r0 < 64) ? (M - r0) : 64;
    int row = r0 + wave * 16 + n;
    int rowc = row < M ? row : (M - 1);

    if (threadIdx.x < 64 && threadIdx.x < nrows) lb[threadIdx.x] = batch[r0 + threadIdx.x];

    floatx4 acc[NTC];
    #pragma unroll
    for (int nt = 0; nt < NTC; ++nt) acc[nt] = (floatx4){0.f, 0.f, 0.f, 0.f};

    const unsigned char* Wp[2] = {Wlp, Wrp};
    const unsigned char* Ap[2] = {Aagg, Ah};

    #pragma unroll
    for (int phase = 0; phase < 2; ++phase){
        if (phase) __syncthreads();   // all waves done reading previous phase

        // hoist A-row loads above staging: latency overlaps the 45.5 KB copy
        const unsigned char* arow = Ap[phase] + (size_t)rowc * ROWP + q * 8;
        long a[KS];
        #pragma unroll
        for (int ks = 0; ks < 6; ++ks)
            a[ks] = *reinterpret_cast<const long*>(arow + ks * 32);
        a[6] = (q < 2) ? *reinterpret_cast<const long*>(arow + 192) : 0L;

        {
            const uint4* src4 = reinterpret_cast<const uint4*>(Wp[phase]);
            uint4* dst4 = reinterpret_cast<uint4*>(lw);
            for (int i = threadIdx.x; i < STAGE_BYTES / 16; i += 256)
                dst4[i] = src4[i];
        }
        __syncthreads();

        #pragma unroll
        for (int ks = 0; ks < KS; ++ks){
            #pragma unroll
            for (int nt = 0; nt < NTC; ++nt){
                long b = *reinterpret_cast<const long*>(&lw[((nt * KS + ks) * 64 + lane) * 8]);
                acc[nt] = __builtin_amdgcn_mfma_f32_16x16x32_fp8_fp8(a[ks], b, acc[nt], 0, 0, 0);
            }
        }
    }
    __syncthreads();   // all MFMA done reading lw; reuse as pool tile

    unsigned char* ptile = lw;
    {
        int lr0 = wave * 16 + q * 4;
        #pragma unroll
        for (int nt = 0; nt < NTC; ++nt){
            float bsv = biasp[nt * 16 + n];
            #pragma unroll
            for (int r = 0; r < 4; ++r){
                float v = fmaxf(acc[nt][r] + bsv, 0.f);
                ptile[(lr0 + r) * PT_STRIDE + nt * 16 + n] = b1_fp8(v);
            }
        }
    }
    __syncthreads();   // pool tile complete

    // vectorized tile -> global h write (pads 208..255 stay zero from memset)
    {
        const uint4* s4 = reinterpret_cast<const uint4*>(ptile);
        int tot = nrows * 13;
        for (int i = threadIdx.x; i < tot; i += 256){
            int r = i / 13, c = i - r * 13;
            *reinterpret_cast<uint4*>(outp + (size_t)(r0 + r) * ROWP + c * 16) = s4[i];
        }
    }

    // segmented pool reduce (batch sorted -> few segments per block)
    if (threadIdx.x < 50){
        int t = threadIdx.x;
        const unsigned* pd = reinterpret_cast<const unsigned*>(ptile);
        float s0 = 0.f, s1 = 0.f, s2 = 0.f, s3 = 0.f;
        int cur = lb[0];
        for (int r = 0; r < nrows; ++r){
            int gg = lb[r];
            if (gg != cur){
                float* gp = &gsum[(size_t)cur * 1000 + col_off + t * 4];
                atomicAdd(gp + 0, s0); atomicAdd(gp + 1, s1);
                atomicAdd(gp + 2, s2); atomicAdd(gp + 3, s3);
                s0 = s1 = s2 = s3 = 0.f;
                cur = gg;
            }
            unsigned u = pd[r * 52 + t];
            floatx2 lo = __builtin_amdgcn_cvt_pk_f32_fp8((int)u, false);
            floatx2 hi = __builtin_amdgcn_cvt_pk_f32_fp8((int)u, true);
            s0 += lo[0]; s1 += lo[1]; s2 += hi[0]; s3 += hi[1];
        }
        float* gp = &gsum[(size_t)cur * 1000 + col_off + t * 4];
        atomicAdd(gp + 0, s0); atomicAdd(gp + 1, s1);
        atomicAdd(gp + 2, s2); atomicAdd(gp + 3, s3);
    }
}

// ============================ MLP head (fp32) ============================

__global__ __launch_bounds__(256) void k_mlp_first(
    const float* __restrict__ gsum, const int* __restrict__ gstart,
    const float* __restrict__ W, const float* __restrict__ b,
    float* __restrict__ outp)
{
    __shared__ __align__(16) float row[1000];
    int g = blockIdx.x;
    int cnt = gstart[g+1] - gstart[g];
    float inv = 1.0f / fmaxf((float)cnt, 1.0f);
    for (int i = threadIdx.x; i < 1000; i += 256)
        row[i] = gsum[(size_t)g * 1000 + i] * inv;
    __syncthreads();
    for (int c = threadIdx.x; c < 500; c += 256){
        const float4* w4 = reinterpret_cast<const float4*>(W + (size_t)c * 1000);
        const float4* r4 = reinterpret_cast<const float4*>(row);
        float s = b[c];
        for (int k = 0; k < 250; ++k){
            float4 wv = w4[k]; float4 rv = r4[k];
            s = fmaf(wv.x, rv.x, s);
            s = fmaf(wv.y, rv.y, s);
            s = fmaf(wv.z, rv.z, s);
            s = fmaf(wv.w, rv.w, s);
        }
        outp[(size_t)g * 500 + c] = s;
    }
}

__global__ __launch_bounds__(256) void k_mlp23(
    const float* __restrict__ t1, const float* __restrict__ W2,
    const float* __restrict__ b2, const float* __restrict__ W3,
    const float* __restrict__ b3, float* __restrict__ outp)
{
    __shared__ __align__(16) float row[500];
    __shared__ float red[256];
    int g = blockIdx.x;
    for (int i = threadIdx.x; i < 500; i += 256) row[i] = t1[(size_t)g * 500 + i];
    __syncthreads();
    float prod = 0.f;
    int c = threadIdx.x;
    if (c < 250){
        const float4* w4 = reinterpret_cast<const float4*>(W2 + (size_t)c * 500);
        const float4* r4 = reinterpret_cast<const float4*>(row);
        float s = b2[c];
        for (int k = 0; k < 125; ++k){
            float4 wv = w4[k]; float4 rv = r4[k];
            s = fmaf(wv.x, rv.x, s);
            s = fmaf(wv.y, rv.y, s);
            s = fmaf(wv.z, rv.z, s);
            s = fmaf(wv.w, rv.w, s);
        }
        prod = s * W3[c];
    }
    red[threadIdx.x] = prod;
    __syncthreads();
    for (int off = 128; off > 0; off >>= 1){
        if (threadIdx.x < off) red[threadIdx.x] += red[threadIdx.x + off];
        __syncthreads();
    }
    if (threadIdx.x == 0)
        outp[g] = 1.0f / (1.0f + expf(-(red[0] + b3[0])));
}

// ============================ launch ============================

extern "C" void kernel_launch(void* const* d_in, const int* in_sizes, int n_in,
                              void* d_out, int out_size, void* d_ws, size_t ws_size,
                              hipStream_t stream)
{
    const float* x    = (const float*)d_in[0];
    const int*   ei   = (const int*)d_in[1];
    const int*   batch= (const int*)d_in[2];
    const float* Wl[5]; const float* bl[5]; const float* Wr[5];
    for (int i = 0; i < 5; ++i){
        Wl[i] = (const float*)d_in[3 + 3*i];
        bl[i] = (const float*)d_in[4 + 3*i];
        Wr[i] = (const float*)d_in[5 + 3*i];
    }
    const float* pw1 = (const float*)d_in[18]; const float* pb1 = (const float*)d_in[19];
    const float* pw2 = (const float*)d_in[20]; const float* pb2 = (const float*)d_in[21];
    const float* pw3 = (const float*)d_in[22]; const float* pb3 = (const float*)d_in[23];
    float* out = (float*)d_out;

    const int N  = in_sizes[2];
    const int E  = in_sizes[1] / 2;
    const int NG = out_size;
    const int* esrc = ei;
    const int* edst = ei + E;
    const int nbuck = (N + 63) >> BSHIFT;          // 1563
    const int nblk  = (E + EPB - 1) / EPB;         // 391

    // ---- workspace carve ----
    char* p = (char*)d_ws;
    auto carve = [&](size_t bytes)->void* {
        void* r = (void*)p;
        p += (bytes + 255) & ~(size_t)255;
        return r;
    };
    int*   deg     = (int*)  carve((size_t)N * 4);
    int*   row_ptr = (int*)  carve(((size_t)N + 1) * 4);
    int*   csum    = (int*)  carve(4096);
    int*   hist    = (int*)  carve((size_t)nblk * nbuck * 4);
    int*   Tb      = (int*)  carve((size_t)nbuck * 4);
    int*   tbase   = (int*)  carve(((size_t)nbuck + 1) * 4);
    float* invdeg  = (float*)carve((size_t)N * 4);
    int*   gstart  = (int*)  carve(((size_t)NG + 1) * 4);
    int*   srcs    = (int*)  carve((size_t)E * 4);
    unsigned* pairs = (unsigned*)carve((size_t)E * 4);
    unsigned short* xp    = (unsigned short*)carve((size_t)N * 16 * 2);
    unsigned char*  xa    = (unsigned char*) carve((size_t)N * 32);
    unsigned char*  agg8  = (unsigned char*) carve((size_t)N * ROWP);
    unsigned char*  h8A   = (unsigned char*) carve((size_t)N * ROWP);
    unsigned char*  h8B   = (unsigned char*) carve((size_t)N * ROWP);
    unsigned char*  wpack = (unsigned char*) carve((size_t)8 * PACK_BYTES);
    unsigned char*  w1pack= (unsigned char*) carve((size_t)PACK1_BYTES);
    float* biasp   = (float*)carve((size_t)5 * ROWP * 4);
    float* gsum    = (float*)carve((size_t)NG * 1000 * 4);
    float* t1      = (float*)carve((size_t)NG * 500 * 4);

    // ---- zero what must be zero ----
    hipMemsetAsync(gsum, 0, (size_t)NG * 1000 * 4, stream);
    // pad columns 200..255 of h rows must stay zero across all layers
    hipMemsetAsync(h8A, 0, (size_t)N * ROWP, stream);
    hipMemsetAsync(h8B, 0, (size_t)N * ROWP, stream);

    // ---- packing ----
    int xblk = (N * 16 + 255) / 256;
    k_pack_w<<<dim3(NT, KS, 8), 64, 0, stream>>>(
        Wl[1], Wr[1], Wl[2], Wr[2], Wl[3], Wr[3], Wl[4], Wr[4], wpack);
    k_pack_misc<<<xblk + NT + 5, 256, 0, stream>>>(
        x, xp, xa, Wl[0], Wr[0], w1pack,
        bl[0], bl[1], bl[2], bl[3], bl[4], biasp, N, xblk);

    // ---- binned CSR build (no hot global atomics) ----
    k_bin_hist<<<nblk, 256, 0, stream>>>(edst, hist, E, nbuck);
    k_col_scan<<<(nbuck + 63) / 64, 256, 0, stream>>>(hist, Tb, nblk, nbuck);
    k_scan_t<<<1, 256, 0, stream>>>(Tb, tbase, nbuck, batch, gstart, N, NG);
    k_bin_scatter<<<nblk, 256, 0, stream>>>(esrc, edst, hist, tbase, pairs, E, nbuck);
    k_bucket_deg<<<nbuck, 256, 0, stream>>>(pairs, tbase, deg, invdeg, N);
    int nchunks = (N + 1023) / 1024;
    k_scan_sums<<<nchunks, 256, 0, stream>>>(deg, csum, N);
    k_scan_apply<<<nchunks, 256, 0, stream>>>(deg, csum, row_ptr, N, E, nchunks);
    k_place<<<nbuck, 256, 0, stream>>>(pairs, tbase, row_ptr, srcs, N);

    // ---- layer 1 (fp8 MFMA over K=32 = [agg11 | x11]) + fused pool ----
    int gb = (N + 63) / 64;
    k_agg11<<<(N + 7) / 8, 256, 0, stream>>>(xp, row_ptr, srcs, invdeg, xa, N);
    k_layer1_mfma<<<gb, 256, 0, stream>>>(xa, w1pack, biasp, batch, gsum, h8A, N);

    // ---- layers 2..5 (fp8 gather + fp8 MFMA + fused pool) ----
    unsigned char* hc = h8A; unsigned char* hn = h8B;
    int ab = (N + 3) / 4;
    for (int L = 1; L < 5; ++L){
        k_agg200<<<ab, 256, 0, stream>>>(hc, row_ptr, srcs, invdeg, agg8, N);
        const unsigned char* Wlp = wpack + (size_t)((L-1)*2 + 0) * PACK_BYTES;
        const unsigned char* Wrp = wpack + (size_t)((L-1)*2 + 1) * PACK_BYTES;
        k_sage_mfma<<<gb, 256, 0, stream>>>(agg8, hc, Wlp, Wrp,
                                            biasp + L * ROWP, batch, gsum, 200 * L,
                                            hn, N);
        unsigned char* t = hc; hc = hn; hn = t;
    }

    // ---- MLP head (pool finalize fused into first layer) ----
    k_mlp_first<<<NG, 256, 0, stream>>>(gsum, gstart, pw1, pb1, t1);
    k_mlp23<<<NG, 256, 0, stream>>>(t1, pw2, pb2, pw3, pb3, out);
}